// Round 1
// baseline (1018.431 us; speedup 1.0000x reference)
//
#include <hip/hip_runtime.h>
#include <math.h>

// ---------------------------------------------------------------------------
// Generic tiled GEMM:  C[M,N] = act( A[M,K] @ W[N,K]^T + bias[N] )
// Both A and W are K-major (row-contiguous) => "NT" dot-product GEMM.
// Tile 64x64, K-tile 16, 256 threads, 4x4 microtile per thread.
// LDS stored K-transposed (As[k][row]) so inner loop does float4 LDS reads.
// ACT: 0=none, 1=tanh, 2=sigmoid, 3=hardtanh(-4.5, 0)
// ---------------------------------------------------------------------------
#define TM 64
#define TN 64
#define TK 16

template <int ACT>
__global__ __launch_bounds__(256) void gemm_nt(
    const float* __restrict__ A,     // [M,K]
    const float* __restrict__ W,     // [N,K]
    const float* __restrict__ bias,  // [N]
    float* __restrict__ C,           // [M,N]
    int M, int N, int K)
{
    __shared__ float As[TK][TM];
    __shared__ float Ws[TK][TN];

    const int t  = threadIdx.x;
    const int ty = t >> 4;   // 0..15 row group
    const int tx = t & 15;   // 0..15 col group
    const int rBase = blockIdx.x * TM;
    const int cBase = blockIdx.y * TN;

    const int lrow = t >> 2;        // 0..63 (tile row for staging)
    const int lk4  = (t & 3) * 4;   // 0,4,8,12 (k chunk for staging)

    float acc[4][4];
#pragma unroll
    for (int a = 0; a < 4; ++a)
#pragma unroll
        for (int b = 0; b < 4; ++b) acc[a][b] = 0.f;

    const float* Arow = A + (size_t)(rBase + lrow) * K;
    const int    wrow = cBase + lrow;
    const float* Wrow = W + (size_t)wrow * K;
    const bool   wvalid = (wrow < N);

    for (int k0 = 0; k0 < K; k0 += TK) {
        float4 av = *(const float4*)(Arow + k0 + lk4);
        float4 wv = make_float4(0.f, 0.f, 0.f, 0.f);
        if (wvalid) wv = *(const float4*)(Wrow + k0 + lk4);

        __syncthreads();   // protect previous iteration's LDS reads
        As[lk4 + 0][lrow] = av.x;
        As[lk4 + 1][lrow] = av.y;
        As[lk4 + 2][lrow] = av.z;
        As[lk4 + 3][lrow] = av.w;
        Ws[lk4 + 0][lrow] = wv.x;
        Ws[lk4 + 1][lrow] = wv.y;
        Ws[lk4 + 2][lrow] = wv.z;
        Ws[lk4 + 3][lrow] = wv.w;
        __syncthreads();

#pragma unroll
        for (int kk = 0; kk < TK; ++kk) {
            float4 a4 = *(const float4*)&As[kk][ty * 4];
            float4 w4 = *(const float4*)&Ws[kk][tx * 4];
            float a_[4] = {a4.x, a4.y, a4.z, a4.w};
            float w_[4] = {w4.x, w4.y, w4.z, w4.w};
#pragma unroll
            for (int a = 0; a < 4; ++a)
#pragma unroll
                for (int b = 0; b < 4; ++b)
                    acc[a][b] = fmaf(a_[a], w_[b], acc[a][b]);
        }
    }

    // epilogue: bias + activation + store
#pragma unroll
    for (int a = 0; a < 4; ++a) {
        const int r = rBase + ty * 4 + a;
#pragma unroll
        for (int b = 0; b < 4; ++b) {
            const int c = cBase + tx * 4 + b;
            if (c < N) {
                float v = acc[a][b] + bias[c];
                if (ACT == 1) v = tanhf(v);
                else if (ACT == 2) v = 1.f / (1.f + expf(-v));
                else if (ACT == 3) v = fminf(fmaxf(v, -4.5f), 0.f);
                C[(size_t)r * N + c] = v;
            }
        }
    }
}

// ---------------------------------------------------------------------------
// Reparameterization: one 64-lane wave per row.
//   inv_cov = diag(exp(lv)) + a a^T ;  cov = inv(inv_cov) (Sherman-Morrison)
//   cov = diag(s) - c u u^T,  s=exp(-lv), u=s*a, c=1/(1+sum(a^2 s))
//   Cholesky (lower) of diag(s) + alpha v v^T has closed form; the scan
//   linearizes via reciprocal:  t_j = -1/(1+R_j),  R_j = sum_{k>=j} a_k^2 s_k
//   L[j][j] = sqrt( s_j (1+R_{j+1}) / (1+R_j) )
//   L[i][j] = u_i * b_j,  b_j = -s_j a_j / ((1+R_j) L[j][j])   (i>j)
//   z_i = mean_i + L[i][i] eps_i + b_i * sum_{j>i} u_j eps_j
// ---------------------------------------------------------------------------
__global__ __launch_bounds__(256) void reparam_kernel(
    const float* __restrict__ mean,
    const float* __restrict__ logvar,   // already clipped
    const float* __restrict__ approx,
    const float* __restrict__ eps,
    float* __restrict__ z,
    int B)
{
    const int gid  = blockIdx.x * 256 + threadIdx.x;
    const int row  = gid >> 6;
    const int lane = threadIdx.x & 63;
    if (row >= B) return;

    const size_t idx = (size_t)row * 64 + lane;
    const float m  = mean[idx];
    const float lv = logvar[idx];
    const float a  = approx[idx];
    const float ep = eps[idx];

    const float s  = expf(-lv);   // 1/exp(lv)
    const float x1 = a * a * s;   // contributes to R
    const float x2 = s * a * ep;  // u_j * eps_j, contributes to S

    // inclusive suffix sums across the 64-lane wave
    float R = x1, S = x2;
#pragma unroll
    for (int off = 1; off < 64; off <<= 1) {
        float r2 = __shfl_down(R, off, 64);
        float s2 = __shfl_down(S, off, 64);
        if (lane + off < 64) { R += r2; S += s2; }
    }
    const float Rexc  = R - x1;  // R_{j+1}
    const float Sexc  = S - x2;  // sum_{j>i} u_j eps_j
    const float inv1R = 1.f / (1.f + R);
    const float dL    = sqrtf(s * (1.f + Rexc) * inv1R);
    const float bj    = -s * a * inv1R / dL;

    z[idx] = m + dL * ep + bj * Sexc;
}

// ---------------------------------------------------------------------------
extern "C" void kernel_launch(void* const* d_in, const int* in_sizes, int n_in,
                              void* d_out, int out_size, void* d_ws, size_t ws_size,
                              hipStream_t stream)
{
    const float* x    = (const float*)d_in[0];
    const float* eps  = (const float*)d_in[1];
    const float* W_ih = (const float*)d_in[2];
    const float* b_ih = (const float*)d_in[3];
    const float* W_m  = (const float*)d_in[4];
    const float* b_m  = (const float*)d_in[5];
    const float* W_lv = (const float*)d_in[6];
    const float* b_lv = (const float*)d_in[7];
    const float* W_ap = (const float*)d_in[8];
    const float* b_ap = (const float*)d_in[9];
    const float* W_lh = (const float*)d_in[10];
    const float* b_lh = (const float*)d_in[11];
    const float* W_ho = (const float*)d_in[12];
    const float* b_ho = (const float*)d_in[13];

    const int B = 16384, D = 784, H = 1024, L = 64;

    float* out    = (float*)d_out;
    float* x_mean = out;                       // [B,D]
    float* z      = out + (size_t)B * D;       // [B,L]
    float* mean   = z + (size_t)B * L;         // [B,L]
    float* logvar = mean + (size_t)B * L;      // [B,L]
    float* approx = logvar + (size_t)B * L;    // [B,L]

    float* hidden = (float*)d_ws;              // [B,H] fp32 = 64 MiB
    float* h2     = hidden;                    // reused after hidden is consumed

    dim3 blk(256);

    // encode: hidden = tanh(x @ W_ih^T + b_ih)   [16384,784]x[784,1024]
    gemm_nt<1><<<dim3(B / TM, H / TN), blk, 0, stream>>>(x, W_ih, b_ih, hidden, B, H, D);

    // heads: mean / logvar(clipped) / approx   [16384,1024]x[1024,64]
    gemm_nt<0><<<dim3(B / TM, 1), blk, 0, stream>>>(hidden, W_m,  b_m,  mean,   B, L, H);
    gemm_nt<3><<<dim3(B / TM, 1), blk, 0, stream>>>(hidden, W_lv, b_lv, logvar, B, L, H);
    gemm_nt<0><<<dim3(B / TM, 1), blk, 0, stream>>>(hidden, W_ap, b_ap, approx, B, L, H);

    // reparameterize: z = mean + chol(cov)^T eps   (closed-form rank-1)
    reparam_kernel<<<dim3((B * 64) / 256), blk, 0, stream>>>(mean, logvar, approx, eps, z, B);

    // decode: h2 = tanh(z @ W_lh^T + b_lh)   [16384,64]x[64,1024]
    gemm_nt<1><<<dim3(B / TM, H / TN), blk, 0, stream>>>(z, W_lh, b_lh, h2, B, H, L);

    // output: x_mean = sigmoid(h2 @ W_ho^T + b_ho)   [16384,1024]x[1024,784]
    gemm_nt<2><<<dim3(B / TM, (D + TN - 1) / TN), blk, 0, stream>>>(h2, W_ho, b_ho, x_mean, B, D, H);
}

// Round 3
// 246.745 us; speedup vs baseline: 4.1275x; 4.1275x over previous
//
#include <hip/hip_runtime.h>
#include <hip/hip_bf16.h>
#include <math.h>

typedef __attribute__((ext_vector_type(8))) short short8;
typedef __attribute__((ext_vector_type(4))) float f32x4;

#define GLOBAL_AS __attribute__((address_space(1)))
#define LDS_AS __attribute__((address_space(3)))

__device__ inline void g2l16(const void* g, void* l) {
    __builtin_amdgcn_global_load_lds((const GLOBAL_AS void*)g, (LDS_AS void*)l, 16, 0, 0);
}

// ---------------------------------------------------------------------------
// MFMA GEMM: C[M,N] = epi( A[M,Kp] @ W[N,Kp]^T + bias[N] )
// A, W bf16 K-major (rows 16B-aligned). Tile 128x128, BK=32, 256 thr = 4 waves.
// LDS layout per buffer: A[k8][row][8] then B[k8][row][8]  (k8 = k/8 chunk).
//   -> fragment ds_read_b128 is 16B-consecutive per 16-lane group: conflict-free.
//   -> global_load_lds dest is lane-linear (slot = k8*128+row), source per-lane.
// EPI: 0 = heads (mean/logvar-clip/approx -> 3 fp32 [B,64] planes)
//      1 = tanh -> bf16 (ldc cols)
//      2 = sigmoid -> fp32, only cols < Nreal
// ---------------------------------------------------------------------------
template <int EPI>
__global__ __launch_bounds__(256) void mgemm(
    const __hip_bfloat16* __restrict__ A,   // [M, lda]
    const __hip_bfloat16* __restrict__ W,   // [Npad, ldb]
    const float* __restrict__ bias,         // [Npad]
    void* __restrict__ outp,
    int lda, int ldb, int nT, int ldc, int Nreal)
{
    __shared__ __align__(16) __hip_bfloat16 sh[2][8192];  // 2 buf x (A 4096 + B 4096)

    const int tid  = threadIdx.x;
    const int wave = tid >> 6;
    const int lane = tid & 63;
    const int rBase = blockIdx.x * 128;
    const int cBase = blockIdx.y * 128;

    const __hip_bfloat16* Ab = A + (size_t)rBase * lda;
    const __hip_bfloat16* Wb = W + (size_t)cBase * ldb;

    const int wr = (wave >> 1) * 64;
    const int wc = (wave & 1) * 64;
    const int h  = lane >> 4;    // k8 chunk for fragments
    const int r0 = lane & 15;

    f32x4 acc[4][4];
#pragma unroll
    for (int m = 0; m < 4; ++m)
#pragma unroll
        for (int n = 0; n < 4; ++n) acc[m][n] = (f32x4){0.f, 0.f, 0.f, 0.f};

    // ---- staging lambda: buffer bb, K-offset k0 (elements) ----
    auto stage = [&](int bb, int k0) {
#pragma unroll
        for (int r = 0; r < 2; ++r) {
            int slot = r * 256 + wave * 64 + lane;     // 0..511
            int k8   = slot >> 7;                      // 0..3
            int row  = slot & 127;
            g2l16(Ab + (size_t)row * lda + k0 + k8 * 8, &sh[bb][(k8 * 128 + row) * 8]);
            g2l16(Wb + (size_t)row * ldb + k0 + k8 * 8, &sh[bb][4096 + (k8 * 128 + row) * 8]);
        }
    };

    auto compute = [&](int bb) {
        const __hip_bfloat16* pa = &sh[bb][(size_t)h * 128 * 8];
        const __hip_bfloat16* pb = &sh[bb][4096 + (size_t)h * 128 * 8];
        short8 a_[4], b_[4];
#pragma unroll
        for (int m = 0; m < 4; ++m)
            a_[m] = *(const short8*)(pa + (wr + m * 16 + r0) * 8);
#pragma unroll
        for (int n = 0; n < 4; ++n)
            b_[n] = *(const short8*)(pb + (wc + n * 16 + r0) * 8);
#pragma unroll
        for (int m = 0; m < 4; ++m)
#pragma unroll
            for (int n = 0; n < 4; ++n)
                acc[m][n] = __builtin_amdgcn_mfma_f32_16x16x32_bf16(a_[m], b_[n], acc[m][n], 0, 0, 0);
    };

    stage(0, 0);
    __syncthreads();
    int cur = 0;
    for (int t = 0; t < nT; ++t) {
        if (t + 1 < nT) stage(cur ^ 1, (t + 1) * 32);
        compute(cur);
        __syncthreads();   // drains vmcnt for the new stage + lgkm
        cur ^= 1;
    }

    // ---- epilogue: C/D layout col=lane&15, row=(lane>>4)*4+j ----
    const int rq = lane >> 4;
    const int c0 = lane & 15;
#pragma unroll
    for (int m = 0; m < 4; ++m) {
#pragma unroll
        for (int n = 0; n < 4; ++n) {
            f32x4 v = acc[m][n];
            const int gc = cBase + wc + n * 16 + c0;
            const float bv = bias[gc];
#pragma unroll
            for (int j = 0; j < 4; ++j) {
                const int gr = rBase + wr + m * 16 + rq * 4 + j;
                float val = v[j] + bv;
                if (EPI == 0) {
                    const int sel = gc >> 6, cc = gc & 63;
                    if (sel < 3) {
                        if (sel == 1) val = fminf(fmaxf(val, -4.5f), 0.f);
                        ((float*)outp)[(size_t)sel * (16384u * 64u) + (size_t)gr * 64 + cc] = val;
                    }
                } else if (EPI == 1) {
                    ((__hip_bfloat16*)outp)[(size_t)gr * ldc + gc] = __float2bfloat16(tanhf(val));
                } else {
                    if (gc < Nreal)
                        ((float*)outp)[(size_t)gr * Nreal + gc] = 1.f / (1.f + expf(-val));
                }
            }
        }
    }
}

// ---------------------------------------------------------------------------
// fp32 -> bf16 with column padding (dcols >= scols, pad zeros)
// ---------------------------------------------------------------------------
__global__ void cvt_pad(const float* __restrict__ src, __hip_bfloat16* __restrict__ dst,
                        int scols, int dcols, long total)
{
    long i = (long)blockIdx.x * 256 + threadIdx.x;
    if (i >= total) return;
    long r = i / dcols;
    int  c = (int)(i - r * dcols);
    float v = (c < scols) ? src[r * (long)scols + c] : 0.f;
    dst[i] = __float2bfloat16(v);
}

// rows-padded cvt for 1024-col matrices (W_ho -> [896,1024])
__global__ void pad_rows1024(const float* __restrict__ src, __hip_bfloat16* __restrict__ dst,
                             int srows, long total)
{
    long i = (long)blockIdx.x * 256 + threadIdx.x;
    if (i >= total) return;
    int r = (int)(i >> 10), c = (int)(i & 1023);
    float v = (r < srows) ? src[(size_t)r * 1024 + c] : 0.f;
    dst[i] = __float2bfloat16(v);
}

// pack W_m,W_lv,W_ap [64,1024] each -> [256,1024] bf16 (rows 192.. zero)
__global__ void pack_heads(const float* __restrict__ Wm, const float* __restrict__ Wlv,
                           const float* __restrict__ Wap, __hip_bfloat16* __restrict__ dst)
{
    int i = blockIdx.x * 256 + threadIdx.x;   // 256*1024 total
    int r = i >> 10, c = i & 1023;
    float v = 0.f;
    if (r < 64)       v = Wm[(size_t)r * 1024 + c];
    else if (r < 128) v = Wlv[(size_t)(r - 64) * 1024 + c];
    else if (r < 192) v = Wap[(size_t)(r - 128) * 1024 + c];
    dst[i] = __float2bfloat16(v);
}

__global__ void pack_bias3(const float* bm, const float* blv, const float* bap, float* dst)
{
    int i = threadIdx.x;  // 256
    float v = 0.f;
    if (i < 64)       v = bm[i];
    else if (i < 128) v = blv[i - 64];
    else if (i < 192) v = bap[i - 128];
    dst[i] = v;
}

__global__ void pad_vec(const float* src, float* dst, int n, int total)
{
    int i = blockIdx.x * 256 + threadIdx.x;
    if (i >= total) return;
    dst[i] = (i < n) ? src[i] : 0.f;
}

// ---------------------------------------------------------------------------
// Reparameterization (closed-form rank-1; verified round 1) + bf16 z copy
// ---------------------------------------------------------------------------
__global__ __launch_bounds__(256) void reparam_kernel(
    const float* __restrict__ mean, const float* __restrict__ logvar,
    const float* __restrict__ approx, const float* __restrict__ eps,
    float* __restrict__ z, __hip_bfloat16* __restrict__ zb, int B)
{
    const int gid  = blockIdx.x * 256 + threadIdx.x;
    const int row  = gid >> 6;
    const int lane = threadIdx.x & 63;
    if (row >= B) return;

    const size_t idx = (size_t)row * 64 + lane;
    const float m  = mean[idx];
    const float lv = logvar[idx];
    const float a  = approx[idx];
    const float ep = eps[idx];

    const float s  = expf(-lv);
    const float x1 = a * a * s;
    const float x2 = s * a * ep;

    float R = x1, S = x2;
#pragma unroll
    for (int off = 1; off < 64; off <<= 1) {
        float r2 = __shfl_down(R, off, 64);
        float s2 = __shfl_down(S, off, 64);
        if (lane + off < 64) { R += r2; S += s2; }
    }
    const float Rexc  = R - x1;
    const float Sexc  = S - x2;
    const float inv1R = 1.f / (1.f + R);
    const float dL    = sqrtf(s * (1.f + Rexc) * inv1R);
    const float bj    = -s * a * inv1R / dL;

    const float zv = m + dL * ep + bj * Sexc;
    z[idx]  = zv;
    zb[idx] = __float2bfloat16(zv);
}

// ---------------------------------------------------------------------------
extern "C" void kernel_launch(void* const* d_in, const int* in_sizes, int n_in,
                              void* d_out, int out_size, void* d_ws, size_t ws_size,
                              hipStream_t stream)
{
    const float* x    = (const float*)d_in[0];
    const float* eps  = (const float*)d_in[1];
    const float* W_ih = (const float*)d_in[2];
    const float* b_ih = (const float*)d_in[3];
    const float* W_m  = (const float*)d_in[4];
    const float* b_m  = (const float*)d_in[5];
    const float* W_lv = (const float*)d_in[6];
    const float* b_lv = (const float*)d_in[7];
    const float* W_ap = (const float*)d_in[8];
    const float* b_ap = (const float*)d_in[9];
    const float* W_lh = (const float*)d_in[10];
    const float* b_lh = (const float*)d_in[11];
    const float* W_ho = (const float*)d_in[12];
    const float* b_ho = (const float*)d_in[13];

    const int B = 16384, D = 784, H = 1024, L = 64;

    float* out    = (float*)d_out;
    float* x_mean = out;
    float* z      = out + (size_t)B * D;
    float* mean   = z + (size_t)B * L;
    float* logvar = mean + (size_t)B * L;
    float* approx = logvar + (size_t)B * L;

    // ---- workspace layout (all 256B aligned; total ~63 MiB) ----
    char* ws = (char*)d_ws;
    __hip_bfloat16* hb    = (__hip_bfloat16*)(ws + 0);          // [16384,1024] 33.5MB (reused as h2b)
    __hip_bfloat16* xb    = (__hip_bfloat16*)(ws + 33554432);   // [16384,800]  26.2MB
    __hip_bfloat16* wihb  = (__hip_bfloat16*)(ws + 59768832);   // [1024,800]   1.64MB
    __hip_bfloat16* whead = (__hip_bfloat16*)(ws + 61407232);   // [256,1024]   0.52MB
    __hip_bfloat16* wlhb  = (__hip_bfloat16*)(ws + 61931520);   // [1024,64]    131KB
    __hip_bfloat16* whob  = (__hip_bfloat16*)(ws + 62062592);   // [896,1024]   1.84MB
    __hip_bfloat16* zb    = (__hip_bfloat16*)(ws + 63897600);   // [16384,64]   2.1MB
    float*          bhead = (float*)(ws + 65994752);            // [256]
    float*          bho   = (float*)(ws + 65995776);            // [896]
    __hip_bfloat16* h2b   = hb;

    // ---- conversions / packing ----
    long totx = (long)B * 800;
    cvt_pad<<<dim3((totx + 255) / 256), dim3(256), 0, stream>>>(x, xb, 784, 800, totx);
    long totwih = 1024L * 800;
    cvt_pad<<<dim3((totwih + 255) / 256), dim3(256), 0, stream>>>(W_ih, wihb, 784, 800, totwih);
    pack_heads<<<dim3(1024), dim3(256), 0, stream>>>(W_m, W_lv, W_ap, whead);
    pack_bias3<<<dim3(1), dim3(256), 0, stream>>>(b_m, b_lv, b_ap, bhead);
    long totwlh = 1024L * 64;
    cvt_pad<<<dim3((totwlh + 255) / 256), dim3(256), 0, stream>>>(W_lh, wlhb, 64, 64, totwlh);
    long totwho = 896L * 1024;
    pad_rows1024<<<dim3((totwho + 255) / 256), dim3(256), 0, stream>>>(W_ho, whob, 784, totwho);
    pad_vec<<<dim3(4), dim3(256), 0, stream>>>(b_ho, bho, 784, 896);

    // ---- encode: hidden = tanh(x @ W_ih^T + b_ih) -> bf16 [B,1024] ----
    mgemm<1><<<dim3(128, 8), dim3(256), 0, stream>>>(xb, wihb, b_ih, hb, 800, 800, 25, 1024, 1024);

    // ---- heads: [mean|logvar|approx] = hidden @ Whead^T -> fp32 planes ----
    mgemm<0><<<dim3(128, 2), dim3(256), 0, stream>>>(hb, whead, bhead, mean, 1024, 1024, 32, 0, 192);

    // ---- reparameterize ----
    reparam_kernel<<<dim3((B * 64) / 256), dim3(256), 0, stream>>>(mean, logvar, approx, eps, z, zb, B);

    // ---- decode: h2 = tanh(z @ W_lh^T + b_lh) -> bf16 [B,1024] ----
    mgemm<1><<<dim3(128, 8), dim3(256), 0, stream>>>(zb, wlhb, b_lh, h2b, 64, 64, 2, 1024, 1024);

    // ---- output: x_mean = sigmoid(h2 @ W_ho^T + b_ho) -> fp32 [B,784] ----
    mgemm<2><<<dim3(128, 7), dim3(256), 0, stream>>>(h2b, whob, bho, x_mean, 1024, 1024, 32, 784, 784);
}

// Round 4
// 234.694 us; speedup vs baseline: 4.3394x; 1.0513x over previous
//
#include <hip/hip_runtime.h>
#include <hip/hip_bf16.h>
#include <math.h>

typedef __attribute__((ext_vector_type(8))) short short8;
typedef __attribute__((ext_vector_type(4))) float f32x4;
typedef __attribute__((ext_vector_type(4))) unsigned short us4;

#define GLOBAL_AS __attribute__((address_space(1)))
#define LDS_AS __attribute__((address_space(3)))

__device__ inline void g2l16(const void* g, void* l) {
    __builtin_amdgcn_global_load_lds((const GLOBAL_AS void*)g, (LDS_AS void*)l, 16, 0, 0);
}

__device__ inline unsigned short f2bf(float f) {   // RNE, matches __float2bfloat16 for finite
    unsigned int u = __float_as_uint(f);
    return (unsigned short)((u + 0x7fffu + ((u >> 16) & 1u)) >> 16);
}

// ---------------------------------------------------------------------------
// 256x256 MFMA GEMM (2-phase, BK=32, 8 waves / 512 thr, 64KB LDS dbuf)
// C[M,N] = epi( A[M,lda] @ W[N,ldb]^T + bias[N] ),  A/W bf16 K-major.
// Wave grid 2Mx4N: wave tile 128x64 = 8x4 fragments of 16x16, acc 128 regs.
// LDS per buf: A[k8 0..3][row 0..255][8] (16KB) then B same (16KB).
//   fragment ds_read_b128 16B-consecutive per 16-lane group -> conflict-free.
// EPI: 1 = tanh -> bf16 (ldc cols)   2 = sigmoid -> fp32, cols < Nreal only
// ---------------------------------------------------------------------------
template <int EPI>
__global__ __launch_bounds__(512, 2) void mgemm2(
    const __hip_bfloat16* __restrict__ A,
    const __hip_bfloat16* __restrict__ W,
    const float* __restrict__ bias,
    void* __restrict__ outp,
    int lda, int ldb, int nT, int ldc, int Nreal)
{
    __shared__ __align__(16) __hip_bfloat16 sh[2][16384];   // 64 KiB total

    const int tid  = threadIdx.x;
    const int wave = tid >> 6;
    const int lane = tid & 63;
    const int rBase = blockIdx.x * 256;
    const int cBase = blockIdx.y * 256;

    const __hip_bfloat16* Ab = A + (size_t)rBase * lda;
    const __hip_bfloat16* Wb = W + (size_t)cBase * ldb;

    const int wr = (wave >> 2) * 128;   // wave row base (0/128)
    const int wc = (wave & 3) * 64;     // wave col base (0/64/128/192)
    const int h  = lane >> 4;           // k8 chunk 0..3
    const int r0 = lane & 15;

    f32x4 acc[8][4];
#pragma unroll
    for (int m = 0; m < 8; ++m)
#pragma unroll
        for (int n = 0; n < 4; ++n) acc[m][n] = (f32x4){0.f, 0.f, 0.f, 0.f};

    auto stage = [&](int bb, int k0) {
#pragma unroll
        for (int r = 0; r < 2; ++r) {
            int slot = r * 512 + tid;      // 0..1023
            int k8   = slot >> 8;          // 0..3
            int row  = slot & 255;
            g2l16(Ab + (size_t)row * lda + k0 + k8 * 8, &sh[bb][(k8 * 256 + row) * 8]);
            g2l16(Wb + (size_t)row * ldb + k0 + k8 * 8, &sh[bb][8192 + (k8 * 256 + row) * 8]);
        }
    };

    auto compute = [&](int bb) {
        const __hip_bfloat16* pa = &sh[bb][(size_t)h * 2048];
        const __hip_bfloat16* pb = &sh[bb][8192 + (size_t)h * 2048];
        short8 a_[8], b_[4];
#pragma unroll
        for (int m = 0; m < 8; ++m)
            a_[m] = *(const short8*)(pa + (wr + m * 16 + r0) * 8);
#pragma unroll
        for (int n = 0; n < 4; ++n)
            b_[n] = *(const short8*)(pb + (wc + n * 16 + r0) * 8);
#pragma unroll
        for (int m = 0; m < 8; ++m)
#pragma unroll
            for (int n = 0; n < 4; ++n)
                acc[m][n] = __builtin_amdgcn_mfma_f32_16x16x32_bf16(a_[m], b_[n], acc[m][n], 0, 0, 0);
    };

    stage(0, 0);
    __syncthreads();
    int cur = 0;
    for (int t = 0; t < nT; ++t) {
        if (t + 1 < nT) stage(cur ^ 1, (t + 1) * 32);
        compute(cur);
        __syncthreads();
        cur ^= 1;
    }

    const int rq = lane >> 4;
    const int c0 = lane & 15;
#pragma unroll
    for (int m = 0; m < 8; ++m) {
#pragma unroll
        for (int n = 0; n < 4; ++n) {
            f32x4 v = acc[m][n];
            const int gc = cBase + wc + n * 16 + c0;
            const float bv = bias[gc];
#pragma unroll
            for (int j = 0; j < 4; ++j) {
                const int gr = rBase + wr + m * 16 + rq * 4 + j;
                float val = v[j] + bv;
                if (EPI == 1) {
                    ((__hip_bfloat16*)outp)[(size_t)gr * ldc + gc] = __float2bfloat16(tanhf(val));
                } else {
                    if (gc < Nreal)
                        ((float*)outp)[(size_t)gr * Nreal + gc] = 1.f / (1.f + expf(-val));
                }
            }
        }
    }
}

// ---------------------------------------------------------------------------
// 128x128 MFMA GEMM (4 waves) — kept for heads (EPI 0) and decode (EPI 1).
// ---------------------------------------------------------------------------
template <int EPI>
__global__ __launch_bounds__(256) void mgemm(
    const __hip_bfloat16* __restrict__ A,
    const __hip_bfloat16* __restrict__ W,
    const float* __restrict__ bias,
    void* __restrict__ outp,
    int lda, int ldb, int nT, int ldc, int Nreal)
{
    __shared__ __align__(16) __hip_bfloat16 sh[2][8192];

    const int tid  = threadIdx.x;
    const int wave = tid >> 6;
    const int lane = tid & 63;
    const int rBase = blockIdx.x * 128;
    const int cBase = blockIdx.y * 128;

    const __hip_bfloat16* Ab = A + (size_t)rBase * lda;
    const __hip_bfloat16* Wb = W + (size_t)cBase * ldb;

    const int wr = (wave >> 1) * 64;
    const int wc = (wave & 1) * 64;
    const int h  = lane >> 4;
    const int r0 = lane & 15;

    f32x4 acc[4][4];
#pragma unroll
    for (int m = 0; m < 4; ++m)
#pragma unroll
        for (int n = 0; n < 4; ++n) acc[m][n] = (f32x4){0.f, 0.f, 0.f, 0.f};

    auto stage = [&](int bb, int k0) {
#pragma unroll
        for (int r = 0; r < 2; ++r) {
            int slot = r * 256 + wave * 64 + lane;
            int k8   = slot >> 7;
            int row  = slot & 127;
            g2l16(Ab + (size_t)row * lda + k0 + k8 * 8, &sh[bb][(k8 * 128 + row) * 8]);
            g2l16(Wb + (size_t)row * ldb + k0 + k8 * 8, &sh[bb][4096 + (k8 * 128 + row) * 8]);
        }
    };

    auto compute = [&](int bb) {
        const __hip_bfloat16* pa = &sh[bb][(size_t)h * 1024];
        const __hip_bfloat16* pb = &sh[bb][4096 + (size_t)h * 1024];
        short8 a_[4], b_[4];
#pragma unroll
        for (int m = 0; m < 4; ++m)
            a_[m] = *(const short8*)(pa + (wr + m * 16 + r0) * 8);
#pragma unroll
        for (int n = 0; n < 4; ++n)
            b_[n] = *(const short8*)(pb + (wc + n * 16 + r0) * 8);
#pragma unroll
        for (int m = 0; m < 4; ++m)
#pragma unroll
            for (int n = 0; n < 4; ++n)
                acc[m][n] = __builtin_amdgcn_mfma_f32_16x16x32_bf16(a_[m], b_[n], acc[m][n], 0, 0, 0);
    };

    stage(0, 0);
    __syncthreads();
    int cur = 0;
    for (int t = 0; t < nT; ++t) {
        if (t + 1 < nT) stage(cur ^ 1, (t + 1) * 32);
        compute(cur);
        __syncthreads();
        cur ^= 1;
    }

    const int rq = lane >> 4;
    const int c0 = lane & 15;
#pragma unroll
    for (int m = 0; m < 4; ++m) {
#pragma unroll
        for (int n = 0; n < 4; ++n) {
            f32x4 v = acc[m][n];
            const int gc = cBase + wc + n * 16 + c0;
            const float bv = bias[gc];
#pragma unroll
            for (int j = 0; j < 4; ++j) {
                const int gr = rBase + wr + m * 16 + rq * 4 + j;
                float val = v[j] + bv;
                if (EPI == 0) {
                    const int sel = gc >> 6, cc = gc & 63;
                    if (sel < 3) {
                        if (sel == 1) val = fminf(fmaxf(val, -4.5f), 0.f);
                        ((float*)outp)[(size_t)sel * (16384u * 64u) + (size_t)gr * 64 + cc] = val;
                    }
                } else if (EPI == 1) {
                    ((__hip_bfloat16*)outp)[(size_t)gr * ldc + gc] = __float2bfloat16(tanhf(val));
                }
            }
        }
    }
}

// ---------------------------------------------------------------------------
// Vectorized fp32 -> bf16 conversions (4 elems/thread; col counts 4-divisible
// so every group is fully in-range or fully padding).
// ---------------------------------------------------------------------------
__global__ void cvt_pad4(const float* __restrict__ src, unsigned short* __restrict__ dst,
                         int scols, int dcols, long total4)
{
    long i = (long)blockIdx.x * 256 + threadIdx.x;
    if (i >= total4) return;
    long e = i * 4;
    long row = e / dcols;
    int  c = (int)(e - row * dcols);
    us4 o = (us4){0, 0, 0, 0};
    if (c < scols) {
        float4 v = *(const float4*)(src + row * (long)scols + c);
        o.x = f2bf(v.x); o.y = f2bf(v.y); o.z = f2bf(v.z); o.w = f2bf(v.w);
    }
    *(us4*)(dst + e) = o;
}

// row-padded cvt for 1024-col matrices (W_ho -> [1024,1024], rows>=srows zero)
__global__ void cvt_rows4(const float* __restrict__ src, unsigned short* __restrict__ dst,
                          int srows, long total4)
{
    long i = (long)blockIdx.x * 256 + threadIdx.x;
    if (i >= total4) return;
    long e = i * 4;
    int r = (int)(e >> 10), c = (int)(e & 1023);
    us4 o = (us4){0, 0, 0, 0};
    if (r < srows) {
        float4 v = *(const float4*)(src + (size_t)r * 1024 + c);
        o.x = f2bf(v.x); o.y = f2bf(v.y); o.z = f2bf(v.z); o.w = f2bf(v.w);
    }
    *(us4*)(dst + e) = o;
}

// pack W_m,W_lv,W_ap [64,1024] each -> [256,1024] bf16 (rows 192.. zero)
__global__ void pack_heads(const float* __restrict__ Wm, const float* __restrict__ Wlv,
                           const float* __restrict__ Wap, __hip_bfloat16* __restrict__ dst)
{
    int i = blockIdx.x * 256 + threadIdx.x;
    int r = i >> 10, c = i & 1023;
    float v = 0.f;
    if (r < 64)       v = Wm[(size_t)r * 1024 + c];
    else if (r < 128) v = Wlv[(size_t)(r - 64) * 1024 + c];
    else if (r < 192) v = Wap[(size_t)(r - 128) * 1024 + c];
    dst[i] = __float2bfloat16(v);
}

__global__ void pack_bias3(const float* bm, const float* blv, const float* bap, float* dst)
{
    int i = threadIdx.x;
    float v = 0.f;
    if (i < 64)       v = bm[i];
    else if (i < 128) v = blv[i - 64];
    else if (i < 192) v = bap[i - 128];
    dst[i] = v;
}

__global__ void pad_vec(const float* src, float* dst, int n, int total)
{
    int i = blockIdx.x * 256 + threadIdx.x;
    if (i >= total) return;
    dst[i] = (i < n) ? src[i] : 0.f;
}

// ---------------------------------------------------------------------------
// Reparameterization (closed-form rank-1; verified) + bf16 z copy
// ---------------------------------------------------------------------------
__global__ __launch_bounds__(256) void reparam_kernel(
    const float* __restrict__ mean, const float* __restrict__ logvar,
    const float* __restrict__ approx, const float* __restrict__ eps,
    float* __restrict__ z, __hip_bfloat16* __restrict__ zb, int B)
{
    const int gid  = blockIdx.x * 256 + threadIdx.x;
    const int row  = gid >> 6;
    const int lane = threadIdx.x & 63;
    if (row >= B) return;

    const size_t idx = (size_t)row * 64 + lane;
    const float m  = mean[idx];
    const float lv = logvar[idx];
    const float a  = approx[idx];
    const float ep = eps[idx];

    const float s  = expf(-lv);
    const float x1 = a * a * s;
    const float x2 = s * a * ep;

    float R = x1, S = x2;
#pragma unroll
    for (int off = 1; off < 64; off <<= 1) {
        float r2 = __shfl_down(R, off, 64);
        float s2 = __shfl_down(S, off, 64);
        if (lane + off < 64) { R += r2; S += s2; }
    }
    const float Rexc  = R - x1;
    const float Sexc  = S - x2;
    const float inv1R = 1.f / (1.f + R);
    const float dL    = sqrtf(s * (1.f + Rexc) * inv1R);
    const float bj    = -s * a * inv1R / dL;

    const float zv = m + dL * ep + bj * Sexc;
    z[idx]  = zv;
    zb[idx] = __float2bfloat16(zv);
}

// ---------------------------------------------------------------------------
extern "C" void kernel_launch(void* const* d_in, const int* in_sizes, int n_in,
                              void* d_out, int out_size, void* d_ws, size_t ws_size,
                              hipStream_t stream)
{
    const float* x    = (const float*)d_in[0];
    const float* eps  = (const float*)d_in[1];
    const float* W_ih = (const float*)d_in[2];
    const float* b_ih = (const float*)d_in[3];
    const float* W_m  = (const float*)d_in[4];
    const float* b_m  = (const float*)d_in[5];
    const float* W_lv = (const float*)d_in[6];
    const float* b_lv = (const float*)d_in[7];
    const float* W_ap = (const float*)d_in[8];
    const float* b_ap = (const float*)d_in[9];
    const float* W_lh = (const float*)d_in[10];
    const float* b_lh = (const float*)d_in[11];
    const float* W_ho = (const float*)d_in[12];
    const float* b_ho = (const float*)d_in[13];

    const int B = 16384;

    float* out    = (float*)d_out;
    float* x_mean = out;
    float* z      = out + (size_t)B * 784;
    float* mean   = z + (size_t)B * 64;
    float* logvar = mean + (size_t)B * 64;
    float* approx = logvar + (size_t)B * 64;

    // ---- workspace layout (~61.2 MiB; round-1 proved >= 66 MB available) ----
    char* ws = (char*)d_ws;
    __hip_bfloat16* hb    = (__hip_bfloat16*)(ws + 0);          // [16384,1024] 33.55MB (reused as h2b)
    __hip_bfloat16* xb    = (__hip_bfloat16*)(ws + 33554432);   // [16384,800]  26.21MB
    __hip_bfloat16* wihb  = (__hip_bfloat16*)(ws + 59768832);   // [1024,800]
    __hip_bfloat16* whead = (__hip_bfloat16*)(ws + 61407232);   // [256,1024]
    __hip_bfloat16* wlhb  = (__hip_bfloat16*)(ws + 61931520);   // [1024,64]
    __hip_bfloat16* whob  = (__hip_bfloat16*)(ws + 62062592);   // [1024,1024]
    float*          bhead = (float*)(ws + 64159744);            // [256]
    float*          bho   = (float*)(ws + 64160768);            // [1024]
    __hip_bfloat16* h2b   = hb;
    __hip_bfloat16* zb    = xb;   // xb dead after encode; reparam runs later

    // ---- conversions / packing (vectorized x4) ----
    long g;
    g = (long)B * 800 / 4;
    cvt_pad4<<<dim3((g + 255) / 256), dim3(256), 0, stream>>>(x, (unsigned short*)xb, 784, 800, g);
    g = 1024L * 800 / 4;
    cvt_pad4<<<dim3((g + 255) / 256), dim3(256), 0, stream>>>(W_ih, (unsigned short*)wihb, 784, 800, g);
    pack_heads<<<dim3(1024), dim3(256), 0, stream>>>(W_m, W_lv, W_ap, whead);
    pack_bias3<<<dim3(1), dim3(256), 0, stream>>>(b_m, b_lv, b_ap, bhead);
    g = 1024L * 64 / 4;
    cvt_pad4<<<dim3((g + 255) / 256), dim3(256), 0, stream>>>(W_lh, (unsigned short*)wlhb, 64, 64, g);
    g = 1024L * 1024 / 4;
    cvt_rows4<<<dim3((g + 255) / 256), dim3(256), 0, stream>>>(W_ho, (unsigned short*)whob, 784, g);
    pad_vec<<<dim3(4), dim3(256), 0, stream>>>(b_ho, bho, 784, 1024);

    // ---- encode: hidden = tanh(x @ W_ih^T + b_ih) -> bf16 [B,1024] (256² GEMM) ----
    mgemm2<1><<<dim3(64, 4), dim3(512), 0, stream>>>(xb, wihb, b_ih, hb, 800, 800, 25, 1024, 1024);

    // ---- heads: [mean|logvar|approx] = hidden @ Whead^T -> fp32 planes (128²) ----
    mgemm<0><<<dim3(128, 2), dim3(256), 0, stream>>>(hb, whead, bhead, mean, 1024, 1024, 32, 0, 192);

    // ---- reparameterize ----
    reparam_kernel<<<dim3((B * 64) / 256), dim3(256), 0, stream>>>(mean, logvar, approx, eps, z, zb, B);

    // ---- decode: h2 = tanh(z @ W_lh^T + b_lh) -> bf16 [B,1024] (128², K=64) ----
    mgemm<1><<<dim3(128, 8), dim3(256), 0, stream>>>(zb, wlhb, b_lh, h2b, 64, 64, 2, 1024, 1024);

    // ---- output: x_mean = sigmoid(h2 @ W_ho^T + b_ho) -> fp32 [B,784] (256²) ----
    mgemm2<2><<<dim3(64, 4), dim3(512), 0, stream>>>(h2b, whob, bho, x_mean, 1024, 1024, 32, 784, 784);
}

// Round 5
// 231.651 us; speedup vs baseline: 4.3964x; 1.0131x over previous
//
#include <hip/hip_runtime.h>
#include <hip/hip_bf16.h>
#include <math.h>

typedef __attribute__((ext_vector_type(8))) short short8;
typedef __attribute__((ext_vector_type(4))) float f32x4;
typedef __attribute__((ext_vector_type(4))) unsigned short us4;

#define GLOBAL_AS __attribute__((address_space(1)))
#define LDS_AS __attribute__((address_space(3)))

__device__ inline void g2l16(const void* g, void* l) {
    __builtin_amdgcn_global_load_lds((const GLOBAL_AS void*)g, (LDS_AS void*)l, 16, 0, 0);
}

__device__ inline unsigned short f2bf(float f) {   // RNE, matches __float2bfloat16 for finite
    unsigned int u = __float_as_uint(f);
    return (unsigned short)((u + 0x7fffu + ((u >> 16) & 1u)) >> 16);
}

// ---------------------------------------------------------------------------
// 256x256 MFMA GEMM, counted-vmcnt 3-deep pipeline (T3+T4 minimum form).
// BK=32, 8 waves / 512 thr. LDS: 3 buffers x (A 16KB + B 16KB) = 96 KiB.
// Per K-step: issue stage(t+2) -> s_waitcnt vmcnt(8) (stage t complete, 8
// newer loads stay in flight) -> s_barrier -> ds_read+MFMA -> s_barrier.
// Buffer (t+2)%3 overwrites the buffer read at iter t-1; its readers finished
// (lgkm drained before their MFMAs) before iter t-1's trailing barrier.
// EPI: 1 = tanh -> bf16 (ldc cols)   2 = sigmoid -> fp32, cols < Nreal only
// ---------------------------------------------------------------------------
template <int EPI>
__global__ __launch_bounds__(512, 2) void mgemm3(
    const __hip_bfloat16* __restrict__ A,
    const __hip_bfloat16* __restrict__ W,
    const float* __restrict__ bias,
    void* __restrict__ outp,
    int lda, int ldb, int nT, int ldc, int Nreal)
{
    __shared__ __align__(16) __hip_bfloat16 sh[3][16384];   // 96 KiB

    const int tid  = threadIdx.x;
    const int wave = tid >> 6;
    const int lane = tid & 63;
    const int rBase = blockIdx.x * 256;
    const int cBase = blockIdx.y * 256;

    const __hip_bfloat16* Ab = A + (size_t)rBase * lda;
    const __hip_bfloat16* Wb = W + (size_t)cBase * ldb;

    const int wr = (wave >> 2) * 128;   // wave row base (0/128)
    const int wc = (wave & 3) * 64;     // wave col base (0/64/128/192)
    const int h  = lane >> 4;           // k8 chunk 0..3
    const int r0 = lane & 15;

    f32x4 acc[8][4];
#pragma unroll
    for (int m = 0; m < 8; ++m)
#pragma unroll
        for (int n = 0; n < 4; ++n) acc[m][n] = (f32x4){0.f, 0.f, 0.f, 0.f};

    auto stage = [&](int bb, int t) {
        const int k0 = t * 32;
#pragma unroll
        for (int r = 0; r < 2; ++r) {
            int slot = r * 512 + tid;      // 0..1023
            int k8   = slot >> 8;          // 0..3
            int row  = slot & 255;
            g2l16(Ab + (size_t)row * lda + k0 + k8 * 8, &sh[bb][(k8 * 256 + row) * 8]);
            g2l16(Wb + (size_t)row * ldb + k0 + k8 * 8, &sh[bb][8192 + (k8 * 256 + row) * 8]);
        }
    };

    auto compute = [&](int bb) {
        const __hip_bfloat16* pa = &sh[bb][(size_t)h * 2048];
        const __hip_bfloat16* pb = &sh[bb][8192 + (size_t)h * 2048];
        short8 a_[8], b_[4];
#pragma unroll
        for (int m = 0; m < 8; ++m)
            a_[m] = *(const short8*)(pa + (wr + m * 16 + r0) * 8);
#pragma unroll
        for (int n = 0; n < 4; ++n)
            b_[n] = *(const short8*)(pb + (wc + n * 16 + r0) * 8);
        __builtin_amdgcn_s_setprio(1);
#pragma unroll
        for (int m = 0; m < 8; ++m)
#pragma unroll
            for (int n = 0; n < 4; ++n)
                acc[m][n] = __builtin_amdgcn_mfma_f32_16x16x32_bf16(a_[m], b_[n], acc[m][n], 0, 0, 0);
        __builtin_amdgcn_s_setprio(0);
    };

    stage(0, 0);
    stage(1, 1);
    for (int t = 0; t < nT; ++t) {
        const int bb = t % 3;
        if (t + 2 < nT) {
            stage((t + 2) % 3, t + 2);
            asm volatile("s_waitcnt vmcnt(8)" ::: "memory");   // stage t done; 8 in flight
        } else if (t + 1 < nT) {
            asm volatile("s_waitcnt vmcnt(4)" ::: "memory");
        } else {
            asm volatile("s_waitcnt vmcnt(0)" ::: "memory");
        }
        __builtin_amdgcn_s_barrier();            // all waves' stage-t loads landed
        asm volatile("" ::: "memory");
        compute(bb);
        asm volatile("" ::: "memory");
        __builtin_amdgcn_s_barrier();            // readers of buf bb done -> reusable
    }

    const int rq = lane >> 4;
    const int c0 = lane & 15;
#pragma unroll
    for (int m = 0; m < 8; ++m) {
#pragma unroll
        for (int n = 0; n < 4; ++n) {
            f32x4 v = acc[m][n];
            const int gc = cBase + wc + n * 16 + c0;
            const float bv = bias[gc];
#pragma unroll
            for (int j = 0; j < 4; ++j) {
                const int gr = rBase + wr + m * 16 + rq * 4 + j;
                float val = v[j] + bv;
                if (EPI == 1) {
                    ((__hip_bfloat16*)outp)[(size_t)gr * ldc + gc] = __float2bfloat16(tanhf(val));
                } else {
                    if (gc < Nreal)
                        ((float*)outp)[(size_t)gr * Nreal + gc] = 1.f / (1.f + expf(-val));
                }
            }
        }
    }
}

// ---------------------------------------------------------------------------
// 128x128 MFMA GEMM (4 waves, 2-phase) — heads (EPI 0) and decode (EPI 1).
// ---------------------------------------------------------------------------
template <int EPI>
__global__ __launch_bounds__(256) void mgemm(
    const __hip_bfloat16* __restrict__ A,
    const __hip_bfloat16* __restrict__ W,
    const float* __restrict__ bias,
    void* __restrict__ outp,
    int lda, int ldb, int nT, int ldc, int Nreal)
{
    __shared__ __align__(16) __hip_bfloat16 sh[2][8192];

    const int tid  = threadIdx.x;
    const int wave = tid >> 6;
    const int lane = tid & 63;
    const int rBase = blockIdx.x * 128;
    const int cBase = blockIdx.y * 128;

    const __hip_bfloat16* Ab = A + (size_t)rBase * lda;
    const __hip_bfloat16* Wb = W + (size_t)cBase * ldb;

    const int wr = (wave >> 1) * 64;
    const int wc = (wave & 1) * 64;
    const int h  = lane >> 4;
    const int r0 = lane & 15;

    f32x4 acc[4][4];
#pragma unroll
    for (int m = 0; m < 4; ++m)
#pragma unroll
        for (int n = 0; n < 4; ++n) acc[m][n] = (f32x4){0.f, 0.f, 0.f, 0.f};

    auto stage = [&](int bb, int k0) {
#pragma unroll
        for (int r = 0; r < 2; ++r) {
            int slot = r * 256 + wave * 64 + lane;
            int k8   = slot >> 7;
            int row  = slot & 127;
            g2l16(Ab + (size_t)row * lda + k0 + k8 * 8, &sh[bb][(k8 * 128 + row) * 8]);
            g2l16(Wb + (size_t)row * ldb + k0 + k8 * 8, &sh[bb][4096 + (k8 * 128 + row) * 8]);
        }
    };

    auto compute = [&](int bb) {
        const __hip_bfloat16* pa = &sh[bb][(size_t)h * 1024];
        const __hip_bfloat16* pb = &sh[bb][4096 + (size_t)h * 1024];
        short8 a_[4], b_[4];
#pragma unroll
        for (int m = 0; m < 4; ++m)
            a_[m] = *(const short8*)(pa + (wr + m * 16 + r0) * 8);
#pragma unroll
        for (int n = 0; n < 4; ++n)
            b_[n] = *(const short8*)(pb + (wc + n * 16 + r0) * 8);
#pragma unroll
        for (int m = 0; m < 4; ++m)
#pragma unroll
            for (int n = 0; n < 4; ++n)
                acc[m][n] = __builtin_amdgcn_mfma_f32_16x16x32_bf16(a_[m], b_[n], acc[m][n], 0, 0, 0);
    };

    stage(0, 0);
    __syncthreads();
    int cur = 0;
    for (int t = 0; t < nT; ++t) {
        if (t + 1 < nT) stage(cur ^ 1, (t + 1) * 32);
        compute(cur);
        __syncthreads();
        cur ^= 1;
    }

    const int rq = lane >> 4;
    const int c0 = lane & 15;
#pragma unroll
    for (int m = 0; m < 4; ++m) {
#pragma unroll
        for (int n = 0; n < 4; ++n) {
            f32x4 v = acc[m][n];
            const int gc = cBase + wc + n * 16 + c0;
            const float bv = bias[gc];
#pragma unroll
            for (int j = 0; j < 4; ++j) {
                const int gr = rBase + wr + m * 16 + rq * 4 + j;
                float val = v[j] + bv;
                if (EPI == 0) {
                    const int sel = gc >> 6, cc = gc & 63;
                    if (sel < 3) {
                        if (sel == 1) val = fminf(fmaxf(val, -4.5f), 0.f);
                        ((float*)outp)[(size_t)sel * (16384u * 64u) + (size_t)gr * 64 + cc] = val;
                    }
                } else if (EPI == 1) {
                    ((__hip_bfloat16*)outp)[(size_t)gr * ldc + gc] = __float2bfloat16(tanhf(val));
                }
            }
        }
    }
}

// ---------------------------------------------------------------------------
// Vectorized fp32 -> bf16 conversions.
// ---------------------------------------------------------------------------
__global__ void cvt_pad4(const float* __restrict__ src, unsigned short* __restrict__ dst,
                         int scols, int dcols, long total4)
{
    long i = (long)blockIdx.x * 256 + threadIdx.x;
    if (i >= total4) return;
    long e = i * 4;
    long row = e / dcols;
    int  c = (int)(e - row * dcols);
    us4 o = (us4){0, 0, 0, 0};
    if (c < scols) {
        float4 v = *(const float4*)(src + row * (long)scols + c);
        o.x = f2bf(v.x); o.y = f2bf(v.y); o.z = f2bf(v.z); o.w = f2bf(v.w);
    }
    *(us4*)(dst + e) = o;
}

__global__ void cvt_rows4(const float* __restrict__ src, unsigned short* __restrict__ dst,
                          int srows, long total4)
{
    long i = (long)blockIdx.x * 256 + threadIdx.x;
    if (i >= total4) return;
    long e = i * 4;
    int r = (int)(e >> 10), c = (int)(e & 1023);
    us4 o = (us4){0, 0, 0, 0};
    if (r < srows) {
        float4 v = *(const float4*)(src + (size_t)r * 1024 + c);
        o.x = f2bf(v.x); o.y = f2bf(v.y); o.z = f2bf(v.z); o.w = f2bf(v.w);
    }
    *(us4*)(dst + e) = o;
}

__global__ void pack_heads(const float* __restrict__ Wm, const float* __restrict__ Wlv,
                           const float* __restrict__ Wap, __hip_bfloat16* __restrict__ dst)
{
    int i = blockIdx.x * 256 + threadIdx.x;
    int r = i >> 10, c = i & 1023;
    float v = 0.f;
    if (r < 64)       v = Wm[(size_t)r * 1024 + c];
    else if (r < 128) v = Wlv[(size_t)(r - 64) * 1024 + c];
    else if (r < 192) v = Wap[(size_t)(r - 128) * 1024 + c];
    dst[i] = __float2bfloat16(v);
}

__global__ void pack_bias3(const float* bm, const float* blv, const float* bap, float* dst)
{
    int i = threadIdx.x;
    float v = 0.f;
    if (i < 64)       v = bm[i];
    else if (i < 128) v = blv[i - 64];
    else if (i < 192) v = bap[i - 128];
    dst[i] = v;
}

__global__ void pad_vec(const float* src, float* dst, int n, int total)
{
    int i = blockIdx.x * 256 + threadIdx.x;
    if (i >= total) return;
    dst[i] = (i < n) ? src[i] : 0.f;
}

// ---------------------------------------------------------------------------
// Reparameterization (closed-form rank-1; verified) + bf16 z copy
// ---------------------------------------------------------------------------
__global__ __launch_bounds__(256) void reparam_kernel(
    const float* __restrict__ mean, const float* __restrict__ logvar,
    const float* __restrict__ approx, const float* __restrict__ eps,
    float* __restrict__ z, __hip_bfloat16* __restrict__ zb, int B)
{
    const int gid  = blockIdx.x * 256 + threadIdx.x;
    const int row  = gid >> 6;
    const int lane = threadIdx.x & 63;
    if (row >= B) return;

    const size_t idx = (size_t)row * 64 + lane;
    const float m  = mean[idx];
    const float lv = logvar[idx];
    const float a  = approx[idx];
    const float ep = eps[idx];

    const float s  = expf(-lv);
    const float x1 = a * a * s;
    const float x2 = s * a * ep;

    float R = x1, S = x2;
#pragma unroll
    for (int off = 1; off < 64; off <<= 1) {
        float r2 = __shfl_down(R, off, 64);
        float s2 = __shfl_down(S, off, 64);
        if (lane + off < 64) { R += r2; S += s2; }
    }
    const float Rexc  = R - x1;
    const float Sexc  = S - x2;
    const float inv1R = 1.f / (1.f + R);
    const float dL    = sqrtf(s * (1.f + Rexc) * inv1R);
    const float bj    = -s * a * inv1R / dL;

    const float zv = m + dL * ep + bj * Sexc;
    z[idx]  = zv;
    zb[idx] = __float2bfloat16(zv);
}

// ---------------------------------------------------------------------------
extern "C" void kernel_launch(void* const* d_in, const int* in_sizes, int n_in,
                              void* d_out, int out_size, void* d_ws, size_t ws_size,
                              hipStream_t stream)
{
    const float* x    = (const float*)d_in[0];
    const float* eps  = (const float*)d_in[1];
    const float* W_ih = (const float*)d_in[2];
    const float* b_ih = (const float*)d_in[3];
    const float* W_m  = (const float*)d_in[4];
    const float* b_m  = (const float*)d_in[5];
    const float* W_lv = (const float*)d_in[6];
    const float* b_lv = (const float*)d_in[7];
    const float* W_ap = (const float*)d_in[8];
    const float* b_ap = (const float*)d_in[9];
    const float* W_lh = (const float*)d_in[10];
    const float* b_lh = (const float*)d_in[11];
    const float* W_ho = (const float*)d_in[12];
    const float* b_ho = (const float*)d_in[13];

    const int B = 16384;

    float* out    = (float*)d_out;
    float* x_mean = out;
    float* z      = out + (size_t)B * 784;
    float* mean   = z + (size_t)B * 64;
    float* logvar = mean + (size_t)B * 64;
    float* approx = logvar + (size_t)B * 64;

    // ---- workspace layout (~61.2 MiB) ----
    char* ws = (char*)d_ws;
    __hip_bfloat16* hb    = (__hip_bfloat16*)(ws + 0);          // [16384,1024] (reused as h2b)
    __hip_bfloat16* xb    = (__hip_bfloat16*)(ws + 33554432);   // [16384,800]
    __hip_bfloat16* wihb  = (__hip_bfloat16*)(ws + 59768832);   // [1024,800]
    __hip_bfloat16* whead = (__hip_bfloat16*)(ws + 61407232);   // [256,1024]
    __hip_bfloat16* wlhb  = (__hip_bfloat16*)(ws + 61931520);   // [1024,64]
    __hip_bfloat16* whob  = (__hip_bfloat16*)(ws + 62062592);   // [1024,1024]
    float*          bhead = (float*)(ws + 64159744);            // [256]
    float*          bho   = (float*)(ws + 64160768);            // [1024]
    __hip_bfloat16* h2b   = hb;
    __hip_bfloat16* zb    = xb;   // xb dead after encode

    // ---- conversions / packing ----
    long g;
    g = (long)B * 800 / 4;
    cvt_pad4<<<dim3((g + 255) / 256), dim3(256), 0, stream>>>(x, (unsigned short*)xb, 784, 800, g);
    g = 1024L * 800 / 4;
    cvt_pad4<<<dim3((g + 255) / 256), dim3(256), 0, stream>>>(W_ih, (unsigned short*)wihb, 784, 800, g);
    pack_heads<<<dim3(1024), dim3(256), 0, stream>>>(W_m, W_lv, W_ap, whead);
    pack_bias3<<<dim3(1), dim3(256), 0, stream>>>(b_m, b_lv, b_ap, bhead);
    g = 1024L * 64 / 4;
    cvt_pad4<<<dim3((g + 255) / 256), dim3(256), 0, stream>>>(W_lh, (unsigned short*)wlhb, 64, 64, g);
    g = 1024L * 1024 / 4;
    cvt_rows4<<<dim3((g + 255) / 256), dim3(256), 0, stream>>>(W_ho, (unsigned short*)whob, 784, g);
    pad_vec<<<dim3(4), dim3(256), 0, stream>>>(b_ho, bho, 784, 1024);

    // ---- encode: hidden = tanh(x @ W_ih^T + b_ih) -> bf16 [B,1024] ----
    mgemm3<1><<<dim3(64, 4), dim3(512), 0, stream>>>(xb, wihb, b_ih, hb, 800, 800, 25, 1024, 1024);

    // ---- heads: [mean|logvar|approx] = hidden @ Whead^T -> fp32 planes ----
    mgemm<0><<<dim3(128, 2), dim3(256), 0, stream>>>(hb, whead, bhead, mean, 1024, 1024, 32, 0, 192);

    // ---- reparameterize ----
    reparam_kernel<<<dim3((B * 64) / 256), dim3(256), 0, stream>>>(mean, logvar, approx, eps, z, zb, B);

    // ---- decode: h2 = tanh(z @ W_lh^T + b_lh) -> bf16 [B,1024] ----
    mgemm<1><<<dim3(128, 8), dim3(256), 0, stream>>>(zb, wlhb, b_lh, h2b, 64, 64, 2, 1024, 1024);

    // ---- output: x_mean = sigmoid(h2 @ W_ho^T + b_ho) -> fp32 [B,784] ----
    mgemm3<2><<<dim3(64, 4), dim3(512), 0, stream>>>(h2b, whob, bho, x_mean, 1024, 1024, 32, 784, 784);
}

// Round 6
// 230.311 us; speedup vs baseline: 4.4220x; 1.0058x over previous
//
#include <hip/hip_runtime.h>
#include <hip/hip_bf16.h>
#include <math.h>

typedef __attribute__((ext_vector_type(8))) short short8;
typedef __attribute__((ext_vector_type(4))) float f32x4;
typedef __attribute__((ext_vector_type(4))) unsigned short us4;

#define GLOBAL_AS __attribute__((address_space(1)))
#define LDS_AS __attribute__((address_space(3)))

__device__ inline void g2l16(const void* g, void* l) {
    __builtin_amdgcn_global_load_lds((const GLOBAL_AS void*)g, (LDS_AS void*)l, 16, 0, 0);
}

__device__ inline unsigned short f2bf(float f) {   // RNE, matches __float2bfloat16 for finite
    unsigned int u = __float_as_uint(f);
    return (unsigned short)((u + 0x7fffu + ((u >> 16) & 1u)) >> 16);
}

// ---------------------------------------------------------------------------
// 256x256 MFMA GEMM, BK=64, phase-interleaved (T3+T4+T5 on 2-deep dbuf).
// 8 waves / 512 thr; wave tile 128x64 (2M x 4N). LDS 2 x 64KB = 128 KiB.
// Per buffer: A[k8 0..7][row 0..255][8] (32KB) then B same (32KB).
// Tile t: issue 8 gloads for t+1 into buf^1 -> s_waitcnt vmcnt(8) (tile t's 8
// loads, issued one full tile ago, landed; 8 newer in flight) -> barrier ->
// 4 phases {12x ds_read_b128 quadrant, setprio1, 16 MFMA, setprio0, barrier}.
// WAR: gloads into buf^1 issued after tile t-1's trailing barrier; t-1's LDS
// reads completed before that barrier (lgkm drained before their MFMAs).
// EPI: 1 = tanh -> bf16 (ldc cols)   2 = sigmoid -> fp32, cols < Nreal only
// ---------------------------------------------------------------------------
template <int EPI>
__global__ __launch_bounds__(512, 2) void mgemm8(
    const __hip_bfloat16* __restrict__ A,
    const __hip_bfloat16* __restrict__ W,
    const float* __restrict__ bias,
    void* __restrict__ outp,
    int lda, int ldb, int nT, int ldc, int Nreal)
{
    __shared__ __align__(16) __hip_bfloat16 sh[2][32768];   // 128 KiB

    const int tid  = threadIdx.x;
    const int wave = tid >> 6;
    const int lane = tid & 63;
    const int rBase = blockIdx.x * 256;
    const int cBase = blockIdx.y * 256;

    const __hip_bfloat16* Ab = A + (size_t)rBase * lda;
    const __hip_bfloat16* Wb = W + (size_t)cBase * ldb;

    const int wr = (wave >> 2) * 128;   // wave row base (0/128)
    const int wc = (wave & 3) * 64;     // wave col base (0/64/128/192)
    const int h  = lane >> 4;           // k8 sub-chunk 0..3 within a k-step
    const int r0 = lane & 15;

    f32x4 acc[8][4];
#pragma unroll
    for (int m = 0; m < 8; ++m)
#pragma unroll
        for (int n = 0; n < 4; ++n) acc[m][n] = (f32x4){0.f, 0.f, 0.f, 0.f};

    // stage one BK=64 K-tile (A: 4 gloads, B: 4 gloads per thread)
    auto stage = [&](int bb, int t) {
        const int k0 = t * 64;
#pragma unroll
        for (int r = 0; r < 4; ++r) {
            int slot = r * 512 + tid;      // 0..2047
            int k8   = slot >> 8;          // 0..7
            int row  = slot & 255;
            g2l16(Ab + (size_t)row * lda + k0 + k8 * 8, &sh[bb][(k8 * 256 + row) * 8]);
        }
#pragma unroll
        for (int r = 0; r < 4; ++r) {
            int slot = r * 512 + tid;
            int k8   = slot >> 8;
            int row  = slot & 255;
            g2l16(Wb + (size_t)row * ldb + k0 + k8 * 8, &sh[bb][16384 + (k8 * 256 + row) * 8]);
        }
    };

    // one phase: quadrant (mh, nh) over full BK=64 (2 k-steps)
    auto phase = [&](int bb, int mh, int nh) {
        const __hip_bfloat16* base = &sh[bb][0];
        short8 a_[4][2], b_[2][2];
#pragma unroll
        for (int i = 0; i < 4; ++i)
#pragma unroll
            for (int ks = 0; ks < 2; ++ks)
                a_[i][ks] = *(const short8*)(base +
                    ((size_t)((ks * 4 + h) * 256 + wr + (mh * 4 + i) * 16 + r0)) * 8);
#pragma unroll
        for (int j = 0; j < 2; ++j)
#pragma unroll
            for (int ks = 0; ks < 2; ++ks)
                b_[j][ks] = *(const short8*)(base + 16384 +
                    ((size_t)((ks * 4 + h) * 256 + wc + (nh * 2 + j) * 16 + r0)) * 8);
        __builtin_amdgcn_s_setprio(1);
#pragma unroll
        for (int ks = 0; ks < 2; ++ks)
#pragma unroll
            for (int i = 0; i < 4; ++i)
#pragma unroll
                for (int j = 0; j < 2; ++j)
                    acc[mh * 4 + i][nh * 2 + j] = __builtin_amdgcn_mfma_f32_16x16x32_bf16(
                        a_[i][ks], b_[j][ks], acc[mh * 4 + i][nh * 2 + j], 0, 0, 0);
        __builtin_amdgcn_s_setprio(0);
    };

    stage(0, 0);
    for (int t = 0; t < nT; ++t) {
        const int bb = t & 1;
        if (t + 1 < nT) {
            stage(bb ^ 1, t + 1);
            asm volatile("s_waitcnt vmcnt(8)" ::: "memory");   // tile t landed; 8 in flight
        } else {
            asm volatile("s_waitcnt vmcnt(0)" ::: "memory");
        }
        __builtin_amdgcn_s_barrier();
#pragma unroll
        for (int p = 0; p < 4; ++p) {
            phase(bb, p >> 1, p & 1);
            __builtin_amdgcn_s_barrier();
        }
    }

    const int rq = lane >> 4;
    const int c0 = lane & 15;
#pragma unroll
    for (int m = 0; m < 8; ++m) {
#pragma unroll
        for (int n = 0; n < 4; ++n) {
            f32x4 v = acc[m][n];
            const int gc = cBase + wc + n * 16 + c0;
            const float bv = bias[gc];
#pragma unroll
            for (int j = 0; j < 4; ++j) {
                const int gr = rBase + wr + m * 16 + rq * 4 + j;
                float val = v[j] + bv;
                if (EPI == 1) {
                    ((__hip_bfloat16*)outp)[(size_t)gr * ldc + gc] = __float2bfloat16(tanhf(val));
                } else {
                    if (gc < Nreal)
                        ((float*)outp)[(size_t)gr * Nreal + gc] = 1.f / (1.f + expf(-val));
                }
            }
        }
    }
}

// ---------------------------------------------------------------------------
// 128x128 MFMA GEMM (4 waves, 2-phase) — heads (EPI 0) and decode (EPI 1).
// ---------------------------------------------------------------------------
template <int EPI>
__global__ __launch_bounds__(256) void mgemm(
    const __hip_bfloat16* __restrict__ A,
    const __hip_bfloat16* __restrict__ W,
    const float* __restrict__ bias,
    void* __restrict__ outp,
    int lda, int ldb, int nT, int ldc, int Nreal)
{
    __shared__ __align__(16) __hip_bfloat16 sh[2][8192];

    const int tid  = threadIdx.x;
    const int wave = tid >> 6;
    const int lane = tid & 63;
    const int rBase = blockIdx.x * 128;
    const int cBase = blockIdx.y * 128;

    const __hip_bfloat16* Ab = A + (size_t)rBase * lda;
    const __hip_bfloat16* Wb = W + (size_t)cBase * ldb;

    const int wr = (wave >> 1) * 64;
    const int wc = (wave & 1) * 64;
    const int h  = lane >> 4;
    const int r0 = lane & 15;

    f32x4 acc[4][4];
#pragma unroll
    for (int m = 0; m < 4; ++m)
#pragma unroll
        for (int n = 0; n < 4; ++n) acc[m][n] = (f32x4){0.f, 0.f, 0.f, 0.f};

    auto stage = [&](int bb, int k0) {
#pragma unroll
        for (int r = 0; r < 2; ++r) {
            int slot = r * 256 + wave * 64 + lane;
            int k8   = slot >> 7;
            int row  = slot & 127;
            g2l16(Ab + (size_t)row * lda + k0 + k8 * 8, &sh[bb][(k8 * 128 + row) * 8]);
            g2l16(Wb + (size_t)row * ldb + k0 + k8 * 8, &sh[bb][4096 + (k8 * 128 + row) * 8]);
        }
    };

    auto compute = [&](int bb) {
        const __hip_bfloat16* pa = &sh[bb][(size_t)h * 1024];
        const __hip_bfloat16* pb = &sh[bb][4096 + (size_t)h * 1024];
        short8 a_[4], b_[4];
#pragma unroll
        for (int m = 0; m < 4; ++m)
            a_[m] = *(const short8*)(pa + (wr + m * 16 + r0) * 8);
#pragma unroll
        for (int n = 0; n < 4; ++n)
            b_[n] = *(const short8*)(pb + (wc + n * 16 + r0) * 8);
#pragma unroll
        for (int m = 0; m < 4; ++m)
#pragma unroll
            for (int n = 0; n < 4; ++n)
                acc[m][n] = __builtin_amdgcn_mfma_f32_16x16x32_bf16(a_[m], b_[n], acc[m][n], 0, 0, 0);
    };

    stage(0, 0);
    __syncthreads();
    int cur = 0;
    for (int t = 0; t < nT; ++t) {
        if (t + 1 < nT) stage(cur ^ 1, (t + 1) * 32);
        compute(cur);
        __syncthreads();
        cur ^= 1;
    }

    const int rq = lane >> 4;
    const int c0 = lane & 15;
#pragma unroll
    for (int m = 0; m < 4; ++m) {
#pragma unroll
        for (int n = 0; n < 4; ++n) {
            f32x4 v = acc[m][n];
            const int gc = cBase + wc + n * 16 + c0;
            const float bv = bias[gc];
#pragma unroll
            for (int j = 0; j < 4; ++j) {
                const int gr = rBase + wr + m * 16 + rq * 4 + j;
                float val = v[j] + bv;
                if (EPI == 0) {
                    const int sel = gc >> 6, cc = gc & 63;
                    if (sel < 3) {
                        if (sel == 1) val = fminf(fmaxf(val, -4.5f), 0.f);
                        ((float*)outp)[(size_t)sel * (16384u * 64u) + (size_t)gr * 64 + cc] = val;
                    }
                } else if (EPI == 1) {
                    ((__hip_bfloat16*)outp)[(size_t)gr * ldc + gc] = __float2bfloat16(tanhf(val));
                }
            }
        }
    }
}

// ---------------------------------------------------------------------------
// Vectorized fp32 -> bf16 conversions.
// ---------------------------------------------------------------------------
__global__ void cvt_pad4(const float* __restrict__ src, unsigned short* __restrict__ dst,
                         int scols, int dcols, long total4)
{
    long i = (long)blockIdx.x * 256 + threadIdx.x;
    if (i >= total4) return;
    long e = i * 4;
    long row = e / dcols;
    int  c = (int)(e - row * dcols);
    us4 o = (us4){0, 0, 0, 0};
    if (c < scols) {
        float4 v = *(const float4*)(src + row * (long)scols + c);
        o.x = f2bf(v.x); o.y = f2bf(v.y); o.z = f2bf(v.z); o.w = f2bf(v.w);
    }
    *(us4*)(dst + e) = o;
}

__global__ void cvt_rows4(const float* __restrict__ src, unsigned short* __restrict__ dst,
                          int srows, long total4)
{
    long i = (long)blockIdx.x * 256 + threadIdx.x;
    if (i >= total4) return;
    long e = i * 4;
    int r = (int)(e >> 10), c = (int)(e & 1023);
    us4 o = (us4){0, 0, 0, 0};
    if (r < srows) {
        float4 v = *(const float4*)(src + (size_t)r * 1024 + c);
        o.x = f2bf(v.x); o.y = f2bf(v.y); o.z = f2bf(v.z); o.w = f2bf(v.w);
    }
    *(us4*)(dst + e) = o;
}

__global__ void pack_heads(const float* __restrict__ Wm, const float* __restrict__ Wlv,
                           const float* __restrict__ Wap, __hip_bfloat16* __restrict__ dst)
{
    int i = blockIdx.x * 256 + threadIdx.x;
    int r = i >> 10, c = i & 1023;
    float v = 0.f;
    if (r < 64)       v = Wm[(size_t)r * 1024 + c];
    else if (r < 128) v = Wlv[(size_t)(r - 64) * 1024 + c];
    else if (r < 192) v = Wap[(size_t)(r - 128) * 1024 + c];
    dst[i] = __float2bfloat16(v);
}

__global__ void pack_bias3(const float* bm, const float* blv, const float* bap, float* dst)
{
    int i = threadIdx.x;
    float v = 0.f;
    if (i < 64)       v = bm[i];
    else if (i < 128) v = blv[i - 64];
    else if (i < 192) v = bap[i - 128];
    dst[i] = v;
}

__global__ void pad_vec(const float* src, float* dst, int n, int total)
{
    int i = blockIdx.x * 256 + threadIdx.x;
    if (i >= total) return;
    dst[i] = (i < n) ? src[i] : 0.f;
}

// ---------------------------------------------------------------------------
// Reparameterization (closed-form rank-1; verified) + bf16 z copy
// ---------------------------------------------------------------------------
__global__ __launch_bounds__(256) void reparam_kernel(
    const float* __restrict__ mean, const float* __restrict__ logvar,
    const float* __restrict__ approx, const float* __restrict__ eps,
    float* __restrict__ z, __hip_bfloat16* __restrict__ zb, int B)
{
    const int gid  = blockIdx.x * 256 + threadIdx.x;
    const int row  = gid >> 6;
    const int lane = threadIdx.x & 63;
    if (row >= B) return;

    const size_t idx = (size_t)row * 64 + lane;
    const float m  = mean[idx];
    const float lv = logvar[idx];
    const float a  = approx[idx];
    const float ep = eps[idx];

    const float s  = expf(-lv);
    const float x1 = a * a * s;
    const float x2 = s * a * ep;

    float R = x1, S = x2;
#pragma unroll
    for (int off = 1; off < 64; off <<= 1) {
        float r2 = __shfl_down(R, off, 64);
        float s2 = __shfl_down(S, off, 64);
        if (lane + off < 64) { R += r2; S += s2; }
    }
    const float Rexc  = R - x1;
    const float Sexc  = S - x2;
    const float inv1R = 1.f / (1.f + R);
    const float dL    = sqrtf(s * (1.f + Rexc) * inv1R);
    const float bj    = -s * a * inv1R / dL;

    const float zv = m + dL * ep + bj * Sexc;
    z[idx]  = zv;
    zb[idx] = __float2bfloat16(zv);
}

// ---------------------------------------------------------------------------
extern "C" void kernel_launch(void* const* d_in, const int* in_sizes, int n_in,
                              void* d_out, int out_size, void* d_ws, size_t ws_size,
                              hipStream_t stream)
{
    const float* x    = (const float*)d_in[0];
    const float* eps  = (const float*)d_in[1];
    const float* W_ih = (const float*)d_in[2];
    const float* b_ih = (const float*)d_in[3];
    const float* W_m  = (const float*)d_in[4];
    const float* b_m  = (const float*)d_in[5];
    const float* W_lv = (const float*)d_in[6];
    const float* b_lv = (const float*)d_in[7];
    const float* W_ap = (const float*)d_in[8];
    const float* b_ap = (const float*)d_in[9];
    const float* W_lh = (const float*)d_in[10];
    const float* b_lh = (const float*)d_in[11];
    const float* W_ho = (const float*)d_in[12];
    const float* b_ho = (const float*)d_in[13];

    const int B = 16384;

    float* out    = (float*)d_out;
    float* x_mean = out;
    float* z      = out + (size_t)B * 784;
    float* mean   = z + (size_t)B * 64;
    float* logvar = mean + (size_t)B * 64;
    float* approx = logvar + (size_t)B * 64;

    // ---- workspace layout (~65.3 MiB; round-1 proved >= 66 MB usable) ----
    char* ws = (char*)d_ws;
    __hip_bfloat16* hb    = (__hip_bfloat16*)(ws + 0);          // [16384,1024] (reused as h2b)
    __hip_bfloat16* xb    = (__hip_bfloat16*)(ws + 33554432);   // [16384,832]  27.3MB
    __hip_bfloat16* wihb  = (__hip_bfloat16*)(ws + 60817408);   // [1024,832]
    __hip_bfloat16* whead = (__hip_bfloat16*)(ws + 62521344);   // [256,1024]
    __hip_bfloat16* wlhb  = (__hip_bfloat16*)(ws + 63045632);   // [1024,64]
    __hip_bfloat16* whob  = (__hip_bfloat16*)(ws + 63176704);   // [1024,1024]
    float*          bhead = (float*)(ws + 65273856);            // [256]
    float*          bho   = (float*)(ws + 65274880);            // [1024]
    __hip_bfloat16* h2b   = hb;
    __hip_bfloat16* zb    = xb;   // xb dead after encode

    // ---- conversions / packing ----
    long g;
    g = (long)B * 832 / 4;
    cvt_pad4<<<dim3((g + 255) / 256), dim3(256), 0, stream>>>(x, (unsigned short*)xb, 784, 832, g);
    g = 1024L * 832 / 4;
    cvt_pad4<<<dim3((g + 255) / 256), dim3(256), 0, stream>>>(W_ih, (unsigned short*)wihb, 784, 832, g);
    pack_heads<<<dim3(1024), dim3(256), 0, stream>>>(W_m, W_lv, W_ap, whead);
    pack_bias3<<<dim3(1), dim3(256), 0, stream>>>(b_m, b_lv, b_ap, bhead);
    g = 1024L * 64 / 4;
    cvt_pad4<<<dim3((g + 255) / 256), dim3(256), 0, stream>>>(W_lh, (unsigned short*)wlhb, 64, 64, g);
    g = 1024L * 1024 / 4;
    cvt_rows4<<<dim3((g + 255) / 256), dim3(256), 0, stream>>>(W_ho, (unsigned short*)whob, 784, g);
    pad_vec<<<dim3(4), dim3(256), 0, stream>>>(b_ho, bho, 784, 1024);

    // ---- encode: hidden = tanh(x @ W_ih^T + b_ih) -> bf16 [B,1024] (Kp=832, 13 tiles) ----
    mgemm8<1><<<dim3(64, 4), dim3(512), 0, stream>>>(xb, wihb, b_ih, hb, 832, 832, 13, 1024, 1024);

    // ---- heads: [mean|logvar|approx] = hidden @ Whead^T -> fp32 planes ----
    mgemm<0><<<dim3(128, 2), dim3(256), 0, stream>>>(hb, whead, bhead, mean, 1024, 1024, 32, 0, 192);

    // ---- reparameterize ----
    reparam_kernel<<<dim3((B * 64) / 256), dim3(256), 0, stream>>>(mean, logvar, approx, eps, z, zb, B);

    // ---- decode: h2 = tanh(z @ W_lh^T + b_lh) -> bf16 [B,1024] ----
    mgemm<1><<<dim3(128, 8), dim3(256), 0, stream>>>(zb, wlhb, b_lh, h2b, 64, 64, 2, 1024, 1024);

    // ---- output: x_mean = sigmoid(h2 @ W_ho^T + b_ho) -> fp32 [B,784] (16 tiles) ----
    mgemm8<2><<<dim3(64, 4), dim3(512), 0, stream>>>(h2b, whob, bho, x_mean, 1024, 1024, 16, 784, 784);
}

// Round 7
// 172.565 us; speedup vs baseline: 5.9017x; 1.3346x over previous
//
#include <hip/hip_runtime.h>
#include <hip/hip_bf16.h>
#include <math.h>

typedef __attribute__((ext_vector_type(8))) short short8;
typedef __attribute__((ext_vector_type(4))) float f32x4;
typedef __attribute__((ext_vector_type(4))) unsigned short us4;

#define GLOBAL_AS __attribute__((address_space(1)))
#define LDS_AS __attribute__((address_space(3)))

__device__ inline void g2l16(const void* g, void* l) {
    __builtin_amdgcn_global_load_lds((const GLOBAL_AS void*)g, (LDS_AS void*)l, 16, 0, 0);
}

__device__ inline unsigned short f2bf(float f) {   // RNE, matches __float2bfloat16 for finite
    unsigned int u = __float_as_uint(f);
    return (unsigned short)((u + 0x7fffu + ((u >> 16) & 1u)) >> 16);
}

// ---------------------------------------------------------------------------
// 256x256 MFMA GEMM, BK=64, 2 phases/tile, counted vmcnt, swizzled staging.
// 8 waves / 512 thr; wave tile 128x64 (2M x 4N). LDS 2 x 64KB = 128 KiB.
// LDS layout per buffer/matrix: [ks(2)][row(256)][c2(4)] 16B slots; the global
// chunk stored at (row, c2) is c2 ^ (row&3)  (XOR involution, both sides).
//  - stage: slot s = r*512+tid -> row=s>>2, src chunk=(s&3)^(row&3): each
//    wave-instr covers 16 rows x full 64B k-half window = 16 cache lines
//    (vs 64 for row-gather staging) -> 4x fewer L2 requests.
//  - read: frag (R, h) at slot R*4 + (h^(R&3)); slot%8 spread uniform
//    (8 lanes/quad-bank-group) -> conflict-free ds_read_b128.
// Schedule per tile t (S0/S1 = ks0/ks1 half-stages, 4 gloads each):
//   prologue: S0(0),S1(0),S0(1)
//   ph0: vmcnt(8) [tail:4]; barrier; ds ks0; issue S1(t+1)->nxt; 32 MFMA
//   ph1: vmcnt(8) [tail:0]; barrier; ds ks1; issue S0(t+2)->cur ks0; 32 MFMA
// Awaited half always has ~4-phase lead; never drain-all in steady state.
// WAR/RAW hazards traced: regions disjoint, barriers separate last-read from
// first-write; per-wave vmcnt + barrier => collective landing certainty.
// EPI: 1 = tanh -> bf16 (ldc cols)   2 = sigmoid -> fp32, cols < Nreal only
// ---------------------------------------------------------------------------
template <int EPI>
__global__ __launch_bounds__(512, 2) void mgemm8(
    const __hip_bfloat16* __restrict__ A,
    const __hip_bfloat16* __restrict__ W,
    const float* __restrict__ bias,
    void* __restrict__ outp,
    int lda, int ldb, int nT, int ldc, int Nreal)
{
    __shared__ __align__(16) __hip_bfloat16 sh[2][32768];   // 128 KiB

    const int tid  = threadIdx.x;
    const int wave = tid >> 6;
    const int lane = tid & 63;
    const int rBase = blockIdx.x * 256;
    const int cBase = blockIdx.y * 256;

    const __hip_bfloat16* Ab = A + (size_t)rBase * lda;
    const __hip_bfloat16* Wb = W + (size_t)cBase * ldb;

    const int wr = (wave >> 2) * 128;   // wave row base (0/128)
    const int wc = (wave & 3) * 64;     // wave col base (0/64/128/192)
    const int h  = lane >> 4;           // chunk-within-kstep 0..3
    const int r0 = lane & 15;
    const int swz = h ^ (r0 & 3);       // swizzled stored-chunk for reads

    f32x4 acc[8][4];
#pragma unroll
    for (int m = 0; m < 8; ++m)
#pragma unroll
        for (int n = 0; n < 4; ++n) acc[m][n] = (f32x4){0.f, 0.f, 0.f, 0.f};

    // stage one k-half (ks of tile t) into buffer bb: 2 A-gloads + 2 B-gloads
    auto stage_half = [&](int bb, int t, int ks) {
        const int k0 = t * 64 + ks * 32;
#pragma unroll
        for (int r = 0; r < 2; ++r) {
            int s2  = r * 512 + tid;            // 0..1023
            int row = s2 >> 2;
            int cg  = (s2 & 3) ^ (row & 3);     // global chunk
            g2l16(Ab + (size_t)row * lda + k0 + cg * 8,
                  &sh[bb][(ks * 1024 + s2) * 8]);
            g2l16(Wb + (size_t)row * ldb + k0 + cg * 8,
                  &sh[bb][16384 + (ks * 1024 + s2) * 8]);
        }
    };

    // one phase: all 32 MFMAs for k-step ks (12 ds_read_b128, zero redundancy)
    auto phase = [&](int bb, int ks) {
        const __hip_bfloat16* base = &sh[bb][ks * 1024 * 8];
        short8 a_[8], b_[4];
#pragma unroll
        for (int i = 0; i < 8; ++i) {
            int R = wr + i * 16 + r0;
            a_[i] = *(const short8*)(base + (R * 4 + swz) * 8);
        }
#pragma unroll
        for (int j = 0; j < 4; ++j) {
            int R = wc + j * 16 + r0;
            b_[j] = *(const short8*)(base + 16384 + (R * 4 + swz) * 8);
        }
        __builtin_amdgcn_s_setprio(1);
#pragma unroll
        for (int i = 0; i < 8; ++i)
#pragma unroll
            for (int j = 0; j < 4; ++j)
                acc[i][j] = __builtin_amdgcn_mfma_f32_16x16x32_bf16(a_[i], b_[j], acc[i][j], 0, 0, 0);
        __builtin_amdgcn_s_setprio(0);
    };

    stage_half(0, 0, 0);
    stage_half(0, 0, 1);
    stage_half(1, 1, 0);
    for (int t = 0; t < nT; ++t) {
        const int cur = t & 1;
        // ---- phase 0 (ks=0) ----
        if (t + 1 < nT) asm volatile("s_waitcnt vmcnt(8)" ::: "memory");
        else            asm volatile("s_waitcnt vmcnt(4)" ::: "memory");
        __builtin_amdgcn_s_barrier();
        if (t + 1 < nT) stage_half(cur ^ 1, t + 1, 1);
        phase(cur, 0);
        // ---- phase 1 (ks=1) ----
        if (t + 1 < nT) asm volatile("s_waitcnt vmcnt(8)" ::: "memory");
        else            asm volatile("s_waitcnt vmcnt(0)" ::: "memory");
        __builtin_amdgcn_s_barrier();
        if (t + 2 < nT) stage_half(cur, t + 2, 0);
        phase(cur, 1);
    }

    const int rq = lane >> 4;
    const int c0 = lane & 15;
#pragma unroll
    for (int m = 0; m < 8; ++m) {
#pragma unroll
        for (int n = 0; n < 4; ++n) {
            f32x4 v = acc[m][n];
            const int gc = cBase + wc + n * 16 + c0;
            const float bv = bias[gc];
#pragma unroll
            for (int j = 0; j < 4; ++j) {
                const int gr = rBase + wr + m * 16 + rq * 4 + j;
                float val = v[j] + bv;
                if (EPI == 1) {
                    ((__hip_bfloat16*)outp)[(size_t)gr * ldc + gc] = __float2bfloat16(tanhf(val));
                } else {
                    if (gc < Nreal)
                        ((float*)outp)[(size_t)gr * Nreal + gc] = 1.f / (1.f + expf(-val));
                }
            }
        }
    }
}

// ---------------------------------------------------------------------------
// 128x128 MFMA GEMM (4 waves, 2-phase drain) — heads (EPI 0), decode (EPI 1).
// Same swizzled staging: layout [row(128)][c2(4)], chunk XOR row&3.
// ---------------------------------------------------------------------------
template <int EPI>
__global__ __launch_bounds__(256) void mgemm(
    const __hip_bfloat16* __restrict__ A,
    const __hip_bfloat16* __restrict__ W,
    const float* __restrict__ bias,
    void* __restrict__ outp,
    int lda, int ldb, int nT, int ldc, int Nreal)
{
    __shared__ __align__(16) __hip_bfloat16 sh[2][8192];

    const int tid  = threadIdx.x;
    const int wave = tid >> 6;
    const int lane = tid & 63;
    const int rBase = blockIdx.x * 128;
    const int cBase = blockIdx.y * 128;

    const __hip_bfloat16* Ab = A + (size_t)rBase * lda;
    const __hip_bfloat16* Wb = W + (size_t)cBase * ldb;

    const int wr = (wave >> 1) * 64;
    const int wc = (wave & 1) * 64;
    const int h  = lane >> 4;
    const int r0 = lane & 15;
    const int swz = h ^ (r0 & 3);

    f32x4 acc[4][4];
#pragma unroll
    for (int m = 0; m < 4; ++m)
#pragma unroll
        for (int n = 0; n < 4; ++n) acc[m][n] = (f32x4){0.f, 0.f, 0.f, 0.f};

    auto stage = [&](int bb, int k0) {
#pragma unroll
        for (int r = 0; r < 2; ++r) {
            int s2  = r * 256 + tid;           // 0..511
            int row = s2 >> 2;
            int cg  = (s2 & 3) ^ (row & 3);
            g2l16(Ab + (size_t)row * lda + k0 + cg * 8, &sh[bb][s2 * 8]);
            g2l16(Wb + (size_t)row * ldb + k0 + cg * 8, &sh[bb][4096 + s2 * 8]);
        }
    };

    auto compute = [&](int bb) {
        const __hip_bfloat16* base = &sh[bb][0];
        short8 a_[4], b_[4];
#pragma unroll
        for (int m = 0; m < 4; ++m) {
            int R = wr + m * 16 + r0;
            a_[m] = *(const short8*)(base + (R * 4 + swz) * 8);
        }
#pragma unroll
        for (int n = 0; n < 4; ++n) {
            int R = wc + n * 16 + r0;
            b_[n] = *(const short8*)(base + 4096 + (R * 4 + swz) * 8);
        }
#pragma unroll
        for (int m = 0; m < 4; ++m)
#pragma unroll
            for (int n = 0; n < 4; ++n)
                acc[m][n] = __builtin_amdgcn_mfma_f32_16x16x32_bf16(a_[m], b_[n], acc[m][n], 0, 0, 0);
    };

    stage(0, 0);
    __syncthreads();
    int cur = 0;
    for (int t = 0; t < nT; ++t) {
        if (t + 1 < nT) stage(cur ^ 1, (t + 1) * 32);
        compute(cur);
        __syncthreads();
        cur ^= 1;
    }

    const int rq = lane >> 4;
    const int c0 = lane & 15;
#pragma unroll
    for (int m = 0; m < 4; ++m) {
#pragma unroll
        for (int n = 0; n < 4; ++n) {
            f32x4 v = acc[m][n];
            const int gc = cBase + wc + n * 16 + c0;
            const float bv = bias[gc];
#pragma unroll
            for (int j = 0; j < 4; ++j) {
                const int gr = rBase + wr + m * 16 + rq * 4 + j;
                float val = v[j] + bv;
                if (EPI == 0) {
                    const int sel = gc >> 6, cc = gc & 63;
                    if (sel < 3) {
                        if (sel == 1) val = fminf(fmaxf(val, -4.5f), 0.f);
                        ((float*)outp)[(size_t)sel * (16384u * 64u) + (size_t)gr * 64 + cc] = val;
                    }
                } else if (EPI == 1) {
                    ((__hip_bfloat16*)outp)[(size_t)gr * ldc + gc] = __float2bfloat16(tanhf(val));
                }
            }
        }
    }
}

// ---------------------------------------------------------------------------
// Vectorized fp32 -> bf16 conversions.
// ---------------------------------------------------------------------------
__global__ void cvt_pad4(const float* __restrict__ src, unsigned short* __restrict__ dst,
                         int scols, int dcols, long total4)
{
    long i = (long)blockIdx.x * 256 + threadIdx.x;
    if (i >= total4) return;
    long e = i * 4;
    long row = e / dcols;
    int  c = (int)(e - row * dcols);
    us4 o = (us4){0, 0, 0, 0};
    if (c < scols) {
        float4 v = *(const float4*)(src + row * (long)scols + c);
        o.x = f2bf(v.x); o.y = f2bf(v.y); o.z = f2bf(v.z); o.w = f2bf(v.w);
    }
    *(us4*)(dst + e) = o;
}

__global__ void cvt_rows4(const float* __restrict__ src, unsigned short* __restrict__ dst,
                          int srows, long total4)
{
    long i = (long)blockIdx.x * 256 + threadIdx.x;
    if (i >= total4) return;
    long e = i * 4;
    int r = (int)(e >> 10), c = (int)(e & 1023);
    us4 o = (us4){0, 0, 0, 0};
    if (r < srows) {
        float4 v = *(const float4*)(src + (size_t)r * 1024 + c);
        o.x = f2bf(v.x); o.y = f2bf(v.y); o.z = f2bf(v.z); o.w = f2bf(v.w);
    }
    *(us4*)(dst + e) = o;
}

__global__ void pack_heads(const float* __restrict__ Wm, const float* __restrict__ Wlv,
                           const float* __restrict__ Wap, __hip_bfloat16* __restrict__ dst)
{
    int i = blockIdx.x * 256 + threadIdx.x;
    int r = i >> 10, c = i & 1023;
    float v = 0.f;
    if (r < 64)       v = Wm[(size_t)r * 1024 + c];
    else if (r < 128) v = Wlv[(size_t)(r - 64) * 1024 + c];
    else if (r < 192) v = Wap[(size_t)(r - 128) * 1024 + c];
    dst[i] = __float2bfloat16(v);
}

__global__ void pack_bias3(const float* bm, const float* blv, const float* bap, float* dst)
{
    int i = threadIdx.x;
    float v = 0.f;
    if (i < 64)       v = bm[i];
    else if (i < 128) v = blv[i - 64];
    else if (i < 192) v = bap[i - 128];
    dst[i] = v;
}

__global__ void pad_vec(const float* src, float* dst, int n, int total)
{
    int i = blockIdx.x * 256 + threadIdx.x;
    if (i >= total) return;
    dst[i] = (i < n) ? src[i] : 0.f;
}

// ---------------------------------------------------------------------------
// Reparameterization (closed-form rank-1; verified) + bf16 z copy
// ---------------------------------------------------------------------------
__global__ __launch_bounds__(256) void reparam_kernel(
    const float* __restrict__ mean, const float* __restrict__ logvar,
    const float* __restrict__ approx, const float* __restrict__ eps,
    float* __restrict__ z, __hip_bfloat16* __restrict__ zb, int B)
{
    const int gid  = blockIdx.x * 256 + threadIdx.x;
    const int row  = gid >> 6;
    const int lane = threadIdx.x & 63;
    if (row >= B) return;

    const size_t idx = (size_t)row * 64 + lane;
    const float m  = mean[idx];
    const float lv = logvar[idx];
    const float a  = approx[idx];
    const float ep = eps[idx];

    const float s  = expf(-lv);
    const float x1 = a * a * s;
    const float x2 = s * a * ep;

    float R = x1, S = x2;
#pragma unroll
    for (int off = 1; off < 64; off <<= 1) {
        float r2 = __shfl_down(R, off, 64);
        float s2 = __shfl_down(S, off, 64);
        if (lane + off < 64) { R += r2; S += s2; }
    }
    const float Rexc  = R - x1;
    const float Sexc  = S - x2;
    const float inv1R = 1.f / (1.f + R);
    const float dL    = sqrtf(s * (1.f + Rexc) * inv1R);
    const float bj    = -s * a * inv1R / dL;

    const float zv = m + dL * ep + bj * Sexc;
    z[idx]  = zv;
    zb[idx] = __float2bfloat16(zv);
}

// ---------------------------------------------------------------------------
extern "C" void kernel_launch(void* const* d_in, const int* in_sizes, int n_in,
                              void* d_out, int out_size, void* d_ws, size_t ws_size,
                              hipStream_t stream)
{
    const float* x    = (const float*)d_in[0];
    const float* eps  = (const float*)d_in[1];
    const float* W_ih = (const float*)d_in[2];
    const float* b_ih = (const float*)d_in[3];
    const float* W_m  = (const float*)d_in[4];
    const float* b_m  = (const float*)d_in[5];
    const float* W_lv = (const float*)d_in[6];
    const float* b_lv = (const float*)d_in[7];
    const float* W_ap = (const float*)d_in[8];
    const float* b_ap = (const float*)d_in[9];
    const float* W_lh = (const float*)d_in[10];
    const float* b_lh = (const float*)d_in[11];
    const float* W_ho = (const float*)d_in[12];
    const float* b_ho = (const float*)d_in[13];

    const int B = 16384;

    float* out    = (float*)d_out;
    float* x_mean = out;
    float* z      = out + (size_t)B * 784;
    float* mean   = z + (size_t)B * 64;
    float* logvar = mean + (size_t)B * 64;
    float* approx = logvar + (size_t)B * 64;

    // ---- workspace layout (~65.3 MiB) ----
    char* ws = (char*)d_ws;
    __hip_bfloat16* hb    = (__hip_bfloat16*)(ws + 0);          // [16384,1024] (reused as h2b)
    __hip_bfloat16* xb    = (__hip_bfloat16*)(ws + 33554432);   // [16384,832]
    __hip_bfloat16* wihb  = (__hip_bfloat16*)(ws + 60817408);   // [1024,832]
    __hip_bfloat16* whead = (__hip_bfloat16*)(ws + 62521344);   // [256,1024]
    __hip_bfloat16* wlhb  = (__hip_bfloat16*)(ws + 63045632);   // [1024,64]
    __hip_bfloat16* whob  = (__hip_bfloat16*)(ws + 63176704);   // [1024,1024]
    float*          bhead = (float*)(ws + 65273856);            // [256]
    float*          bho   = (float*)(ws + 65274880);            // [1024]
    __hip_bfloat16* h2b   = hb;
    __hip_bfloat16* zb    = xb;   // xb dead after encode

    // ---- conversions / packing ----
    long g;
    g = (long)B * 832 / 4;
    cvt_pad4<<<dim3((g + 255) / 256), dim3(256), 0, stream>>>(x, (unsigned short*)xb, 784, 832, g);
    g = 1024L * 832 / 4;
    cvt_pad4<<<dim3((g + 255) / 256), dim3(256), 0, stream>>>(W_ih, (unsigned short*)wihb, 784, 832, g);
    pack_heads<<<dim3(1024), dim3(256), 0, stream>>>(W_m, W_lv, W_ap, whead);
    pack_bias3<<<dim3(1), dim3(256), 0, stream>>>(b_m, b_lv, b_ap, bhead);
    g = 1024L * 64 / 4;
    cvt_pad4<<<dim3((g + 255) / 256), dim3(256), 0, stream>>>(W_lh, (unsigned short*)wlhb, 64, 64, g);
    g = 1024L * 1024 / 4;
    cvt_rows4<<<dim3((g + 255) / 256), dim3(256), 0, stream>>>(W_ho, (unsigned short*)whob, 784, g);
    pad_vec<<<dim3(4), dim3(256), 0, stream>>>(b_ho, bho, 784, 1024);

    // ---- encode: hidden = tanh(x @ W_ih^T + b_ih) -> bf16 [B,1024] (Kp=832, 13 tiles) ----
    mgemm8<1><<<dim3(64, 4), dim3(512), 0, stream>>>(xb, wihb, b_ih, hb, 832, 832, 13, 1024, 1024);

    // ---- heads: [mean|logvar|approx] = hidden @ Whead^T -> fp32 planes ----
    mgemm<0><<<dim3(128, 2), dim3(256), 0, stream>>>(hb, whead, bhead, mean, 1024, 1024, 32, 0, 192);

    // ---- reparameterize ----
    reparam_kernel<<<dim3((B * 64) / 256), dim3(256), 0, stream>>>(mean, logvar, approx, eps, z, zb, B);

    // ---- decode: h2 = tanh(z @ W_lh^T + b_lh) -> bf16 [B,1024] ----
    mgemm<1><<<dim3(128, 8), dim3(256), 0, stream>>>(zb, wlhb, b_lh, h2b, 64, 64, 2, 1024, 1024);

    // ---- output: x_mean = sigmoid(h2 @ W_ho^T + b_ho) -> fp32 [B,784] (16 tiles) ----
    mgemm8<2><<<dim3(64, 4), dim3(512), 0, stream>>>(h2b, whob, bho, x_mean, 1024, 1024, 16, 784, 784);
}

// Round 8
// 167.047 us; speedup vs baseline: 6.0967x; 1.0330x over previous
//
#include <hip/hip_runtime.h>
#include <hip/hip_bf16.h>
#include <math.h>

typedef __attribute__((ext_vector_type(8))) short short8;
typedef __attribute__((ext_vector_type(4))) float f32x4;
typedef __attribute__((ext_vector_type(4))) unsigned short us4;

#define GLOBAL_AS __attribute__((address_space(1)))
#define LDS_AS __attribute__((address_space(3)))

__device__ inline void g2l16(const void* g, void* l) {
    __builtin_amdgcn_global_load_lds((const GLOBAL_AS void*)g, (LDS_AS void*)l, 16, 0, 0);
}

__device__ inline unsigned short f2bf(float f) {   // RNE, matches __float2bfloat16 for finite
    unsigned int u = __float_as_uint(f);
    return (unsigned short)((u + 0x7fffu + ((u >> 16) & 1u)) >> 16);
}

// ---------------------------------------------------------------------------
// 256x256 MFMA GEMM, BK=64, 2 phases/tile, counted vmcnt, swizzled staging.
// 8 waves / 512 thr; wave tile 128x64 (2M x 4N). LDS 2 x 64KB = 128 KiB.
// LDS layout per buffer/matrix: [ks(2)][row(256)][c2(4)] 16B slots; stored
// chunk (row,c2) holds global chunk c2 ^ g(row), g(row) = (row>>1)&3.
//  - stage: slot s -> row=s>>2, src chunk=(s&3)^g(row): each wave-instr
//    covers 16 rows x full 64B window = 16 cache lines (coalesced).
//  - read: frag (R,h) at slot R*4 + (h^g(R)). slot%8 = 4*(R&1) + h^((r0>>1)&3)
//    -> per 16-lane group all 8 bank-quartets hit exactly 2x; the 2 sharing
//    lanes (r0, r0+8) are 512B apart = same bank = free 2-way (m136).
//    (round-7's g=row&3 gave 4 lanes/quartet -> 3.1M conflicts.)
// Schedule per tile t (S0/S1 = ks0/ks1 half-stages, 4 gloads each):
//   prologue: S0(0),S1(0),S0(1)
//   ph0: vmcnt(8) [tail:4]; barrier; ds ks0; issue S1(t+1)->nxt; 32 MFMA
//   ph1: vmcnt(8) [tail:0]; barrier; ds ks1; issue S0(t+2)->cur ks0; 32 MFMA
// EPI: 1 = tanh -> bf16 (ldc cols)   2 = sigmoid -> fp32, cols < Nreal only
// ---------------------------------------------------------------------------
template <int EPI>
__global__ __launch_bounds__(512, 2) void mgemm8(
    const __hip_bfloat16* __restrict__ A,
    const __hip_bfloat16* __restrict__ W,
    const float* __restrict__ bias,
    void* __restrict__ outp,
    int lda, int ldb, int nT, int ldc, int Nreal)
{
    __shared__ __align__(16) __hip_bfloat16 sh[2][32768];   // 128 KiB

    const int tid  = threadIdx.x;
    const int wave = tid >> 6;
    const int lane = tid & 63;
    const int rBase = blockIdx.x * 256;
    const int cBase = blockIdx.y * 256;

    const __hip_bfloat16* Ab = A + (size_t)rBase * lda;
    const __hip_bfloat16* Wb = W + (size_t)cBase * ldb;

    const int wr = (wave >> 2) * 128;   // wave row base (0/128)
    const int wc = (wave & 3) * 64;     // wave col base (0/64/128/192)
    const int h  = lane >> 4;           // chunk-within-kstep 0..3
    const int r0 = lane & 15;
    const int swz = h ^ ((r0 >> 1) & 3);  // g(R)=(R>>1)&3; R low bits = r0

    f32x4 acc[8][4];
#pragma unroll
    for (int m = 0; m < 8; ++m)
#pragma unroll
        for (int n = 0; n < 4; ++n) acc[m][n] = (f32x4){0.f, 0.f, 0.f, 0.f};

    // stage one k-half (ks of tile t) into buffer bb: 2 A-gloads + 2 B-gloads
    auto stage_half = [&](int bb, int t, int ks) {
        const int k0 = t * 64 + ks * 32;
#pragma unroll
        for (int r = 0; r < 2; ++r) {
            int s2  = r * 512 + tid;                 // 0..1023
            int row = s2 >> 2;
            int cg  = (s2 & 3) ^ ((row >> 1) & 3);   // global chunk
            g2l16(Ab + (size_t)row * lda + k0 + cg * 8,
                  &sh[bb][(ks * 1024 + s2) * 8]);
            g2l16(Wb + (size_t)row * ldb + k0 + cg * 8,
                  &sh[bb][16384 + (ks * 1024 + s2) * 8]);
        }
    };

    // one phase: all 32 MFMAs for k-step ks (12 ds_read_b128, zero redundancy)
    auto phase = [&](int bb, int ks) {
        const __hip_bfloat16* base = &sh[bb][ks * 1024 * 8];
        short8 a_[8], b_[4];
#pragma unroll
        for (int i = 0; i < 8; ++i) {
            int R = wr + i * 16 + r0;
            a_[i] = *(const short8*)(base + (R * 4 + swz) * 8);
        }
#pragma unroll
        for (int j = 0; j < 4; ++j) {
            int R = wc + j * 16 + r0;
            b_[j] = *(const short8*)(base + 16384 + (R * 4 + swz) * 8);
        }
        __builtin_amdgcn_s_setprio(1);
#pragma unroll
        for (int i = 0; i < 8; ++i)
#pragma unroll
            for (int j = 0; j < 4; ++j)
                acc[i][j] = __builtin_amdgcn_mfma_f32_16x16x32_bf16(a_[i], b_[j], acc[i][j], 0, 0, 0);
        __builtin_amdgcn_s_setprio(0);
    };

    stage_half(0, 0, 0);
    stage_half(0, 0, 1);
    stage_half(1, 1, 0);
    for (int t = 0; t < nT; ++t) {
        const int cur = t & 1;
        // ---- phase 0 (ks=0) ----
        if (t + 1 < nT) asm volatile("s_waitcnt vmcnt(8)" ::: "memory");
        else            asm volatile("s_waitcnt vmcnt(4)" ::: "memory");
        __builtin_amdgcn_s_barrier();
        if (t + 1 < nT) stage_half(cur ^ 1, t + 1, 1);
        phase(cur, 0);
        // ---- phase 1 (ks=1) ----
        if (t + 1 < nT) asm volatile("s_waitcnt vmcnt(8)" ::: "memory");
        else            asm volatile("s_waitcnt vmcnt(0)" ::: "memory");
        __builtin_amdgcn_s_barrier();
        if (t + 2 < nT) stage_half(cur, t + 2, 0);
        phase(cur, 1);
    }

    const int rq = lane >> 4;
    const int c0 = lane & 15;
#pragma unroll
    for (int m = 0; m < 8; ++m) {
#pragma unroll
        for (int n = 0; n < 4; ++n) {
            f32x4 v = acc[m][n];
            const int gc = cBase + wc + n * 16 + c0;
            const float bv = bias[gc];
#pragma unroll
            for (int j = 0; j < 4; ++j) {
                const int gr = rBase + wr + m * 16 + rq * 4 + j;
                float val = v[j] + bv;
                if (EPI == 1) {
                    ((__hip_bfloat16*)outp)[(size_t)gr * ldc + gc] = __float2bfloat16(tanhf(val));
                } else {
                    if (gc < Nreal)
                        ((float*)outp)[(size_t)gr * Nreal + gc] = 1.f / (1.f + expf(-val));
                }
            }
        }
    }
}

// ---------------------------------------------------------------------------
// 128x128 MFMA GEMM (4 waves, 2-phase drain) — heads (EPI 0), decode (EPI 1).
// Same swizzled staging: layout [row(128)][c2(4)], chunk XOR (row>>1)&3.
// ---------------------------------------------------------------------------
template <int EPI>
__global__ __launch_bounds__(256) void mgemm(
    const __hip_bfloat16* __restrict__ A,
    const __hip_bfloat16* __restrict__ W,
    const float* __restrict__ bias,
    void* __restrict__ outp,
    int lda, int ldb, int nT, int ldc, int Nreal)
{
    __shared__ __align__(16) __hip_bfloat16 sh[2][8192];

    const int tid  = threadIdx.x;
    const int wave = tid >> 6;
    const int lane = tid & 63;
    const int rBase = blockIdx.x * 128;
    const int cBase = blockIdx.y * 128;

    const __hip_bfloat16* Ab = A + (size_t)rBase * lda;
    const __hip_bfloat16* Wb = W + (size_t)cBase * ldb;

    const int wr = (wave >> 1) * 64;
    const int wc = (wave & 1) * 64;
    const int h  = lane >> 4;
    const int r0 = lane & 15;
    const int swz = h ^ ((r0 >> 1) & 3);

    f32x4 acc[4][4];
#pragma unroll
    for (int m = 0; m < 4; ++m)
#pragma unroll
        for (int n = 0; n < 4; ++n) acc[m][n] = (f32x4){0.f, 0.f, 0.f, 0.f};

    auto stage = [&](int bb, int k0) {
#pragma unroll
        for (int r = 0; r < 2; ++r) {
            int s2  = r * 256 + tid;           // 0..511
            int row = s2 >> 2;
            int cg  = (s2 & 3) ^ ((row >> 1) & 3);
            g2l16(Ab + (size_t)row * lda + k0 + cg * 8, &sh[bb][s2 * 8]);
            g2l16(Wb + (size_t)row * ldb + k0 + cg * 8, &sh[bb][4096 + s2 * 8]);
        }
    };

    auto compute = [&](int bb) {
        const __hip_bfloat16* base = &sh[bb][0];
        short8 a_[4], b_[4];
#pragma unroll
        for (int m = 0; m < 4; ++m) {
            int R = wr + m * 16 + r0;
            a_[m] = *(const short8*)(base + (R * 4 + swz) * 8);
        }
#pragma unroll
        for (int n = 0; n < 4; ++n) {
            int R = wc + n * 16 + r0;
            b_[n] = *(const short8*)(base + 4096 + (R * 4 + swz) * 8);
        }
#pragma unroll
        for (int m = 0; m < 4; ++m)
#pragma unroll
            for (int n = 0; n < 4; ++n)
                acc[m][n] = __builtin_amdgcn_mfma_f32_16x16x32_bf16(a_[m], b_[n], acc[m][n], 0, 0, 0);
    };

    stage(0, 0);
    __syncthreads();
    int cur = 0;
    for (int t = 0; t < nT; ++t) {
        if (t + 1 < nT) stage(cur ^ 1, (t + 1) * 32);
        compute(cur);
        __syncthreads();
        cur ^= 1;
    }

    const int rq = lane >> 4;
    const int c0 = lane & 15;
#pragma unroll
    for (int m = 0; m < 4; ++m) {
#pragma unroll
        for (int n = 0; n < 4; ++n) {
            f32x4 v = acc[m][n];
            const int gc = cBase + wc + n * 16 + c0;
            const float bv = bias[gc];
#pragma unroll
            for (int j = 0; j < 4; ++j) {
                const int gr = rBase + wr + m * 16 + rq * 4 + j;
                float val = v[j] + bv;
                if (EPI == 0) {
                    const int sel = gc >> 6, cc = gc & 63;
                    if (sel < 3) {
                        if (sel == 1) val = fminf(fmaxf(val, -4.5f), 0.f);
                        ((float*)outp)[(size_t)sel * (16384u * 64u) + (size_t)gr * 64 + cc] = val;
                    }
                } else if (EPI == 1) {
                    ((__hip_bfloat16*)outp)[(size_t)gr * ldc + gc] = __float2bfloat16(tanhf(val));
                }
            }
        }
    }
}

// ---------------------------------------------------------------------------
// Vectorized fp32 -> bf16 conversions.
// ---------------------------------------------------------------------------
__global__ void cvt_pad4(const float* __restrict__ src, unsigned short* __restrict__ dst,
                         int scols, int dcols, long total4)
{
    long i = (long)blockIdx.x * 256 + threadIdx.x;
    if (i >= total4) return;
    long e = i * 4;
    long row = e / dcols;
    int  c = (int)(e - row * dcols);
    us4 o = (us4){0, 0, 0, 0};
    if (c < scols) {
        float4 v = *(const float4*)(src + row * (long)scols + c);
        o.x = f2bf(v.x); o.y = f2bf(v.y); o.z = f2bf(v.z); o.w = f2bf(v.w);
    }
    *(us4*)(dst + e) = o;
}

__global__ void cvt_rows4(const float* __restrict__ src, unsigned short* __restrict__ dst,
                          int srows, long total4)
{
    long i = (long)blockIdx.x * 256 + threadIdx.x;
    if (i >= total4) return;
    long e = i * 4;
    int r = (int)(e >> 10), c = (int)(e & 1023);
    us4 o = (us4){0, 0, 0, 0};
    if (r < srows) {
        float4 v = *(const float4*)(src + (size_t)r * 1024 + c);
        o.x = f2bf(v.x); o.y = f2bf(v.y); o.z = f2bf(v.z); o.w = f2bf(v.w);
    }
    *(us4*)(dst + e) = o;
}

__global__ void pack_heads(const float* __restrict__ Wm, const float* __restrict__ Wlv,
                           const float* __restrict__ Wap, __hip_bfloat16* __restrict__ dst)
{
    int i = blockIdx.x * 256 + threadIdx.x;
    int r = i >> 10, c = i & 1023;
    float v = 0.f;
    if (r < 64)       v = Wm[(size_t)r * 1024 + c];
    else if (r < 128) v = Wlv[(size_t)(r - 64) * 1024 + c];
    else if (r < 192) v = Wap[(size_t)(r - 128) * 1024 + c];
    dst[i] = __float2bfloat16(v);
}

__global__ void pack_bias3(const float* bm, const float* blv, const float* bap, float* dst)
{
    int i = threadIdx.x;
    float v = 0.f;
    if (i < 64)       v = bm[i];
    else if (i < 128) v = blv[i - 64];
    else if (i < 192) v = bap[i - 128];
    dst[i] = v;
}

__global__ void pad_vec(const float* src, float* dst, int n, int total)
{
    int i = blockIdx.x * 256 + threadIdx.x;
    if (i >= total) return;
    dst[i] = (i < n) ? src[i] : 0.f;
}

// ---------------------------------------------------------------------------
// Reparameterization (closed-form rank-1; verified) + bf16 z copy
// ---------------------------------------------------------------------------
__global__ __launch_bounds__(256) void reparam_kernel(
    const float* __restrict__ mean, const float* __restrict__ logvar,
    const float* __restrict__ approx, const float* __restrict__ eps,
    float* __restrict__ z, __hip_bfloat16* __restrict__ zb, int B)
{
    const int gid  = blockIdx.x * 256 + threadIdx.x;
    const int row  = gid >> 6;
    const int lane = threadIdx.x & 63;
    if (row >= B) return;

    const size_t idx = (size_t)row * 64 + lane;
    const float m  = mean[idx];
    const float lv = logvar[idx];
    const float a  = approx[idx];
    const float ep = eps[idx];

    const float s  = expf(-lv);
    const float x1 = a * a * s;
    const float x2 = s * a * ep;

    float R = x1, S = x2;
#pragma unroll
    for (int off = 1; off < 64; off <<= 1) {
        float r2 = __shfl_down(R, off, 64);
        float s2 = __shfl_down(S, off, 64);
        if (lane + off < 64) { R += r2; S += s2; }
    }
    const float Rexc  = R - x1;
    const float Sexc  = S - x2;
    const float inv1R = 1.f / (1.f + R);
    const float dL    = sqrtf(s * (1.f + Rexc) * inv1R);
    const float bj    = -s * a * inv1R / dL;

    const float zv = m + dL * ep + bj * Sexc;
    z[idx]  = zv;
    zb[idx] = __float2bfloat16(zv);
}

// ---------------------------------------------------------------------------
extern "C" void kernel_launch(void* const* d_in, const int* in_sizes, int n_in,
                              void* d_out, int out_size, void* d_ws, size_t ws_size,
                              hipStream_t stream)
{
    const float* x    = (const float*)d_in[0];
    const float* eps  = (const float*)d_in[1];
    const float* W_ih = (const float*)d_in[2];
    const float* b_ih = (const float*)d_in[3];
    const float* W_m  = (const float*)d_in[4];
    const float* b_m  = (const float*)d_in[5];
    const float* W_lv = (const float*)d_in[6];
    const float* b_lv = (const float*)d_in[7];
    const float* W_ap = (const float*)d_in[8];
    const float* b_ap = (const float*)d_in[9];
    const float* W_lh = (const float*)d_in[10];
    const float* b_lh = (const float*)d_in[11];
    const float* W_ho = (const float*)d_in[12];
    const float* b_ho = (const float*)d_in[13];

    const int B = 16384;

    float* out    = (float*)d_out;
    float* x_mean = out;
    float* z      = out + (size_t)B * 784;
    float* mean   = z + (size_t)B * 64;
    float* logvar = mean + (size_t)B * 64;
    float* approx = logvar + (size_t)B * 64;

    // ---- workspace layout (~65.3 MiB) ----
    char* ws = (char*)d_ws;
    __hip_bfloat16* hb    = (__hip_bfloat16*)(ws + 0);          // [16384,1024] (reused as h2b)
    __hip_bfloat16* xb    = (__hip_bfloat16*)(ws + 33554432);   // [16384,832]
    __hip_bfloat16* wihb  = (__hip_bfloat16*)(ws + 60817408);   // [1024,832]
    __hip_bfloat16* whead = (__hip_bfloat16*)(ws + 62521344);   // [256,1024]
    __hip_bfloat16* wlhb  = (__hip_bfloat16*)(ws + 63045632);   // [1024,64]
    __hip_bfloat16* whob  = (__hip_bfloat16*)(ws + 63176704);   // [1024,1024]
    float*          bhead = (float*)(ws + 65273856);            // [256]
    float*          bho   = (float*)(ws + 65274880);            // [1024]
    __hip_bfloat16* h2b   = hb;
    __hip_bfloat16* zb    = xb;   // xb dead after encode

    // ---- conversions / packing ----
    long g;
    g = (long)B * 832 / 4;
    cvt_pad4<<<dim3((g + 255) / 256), dim3(256), 0, stream>>>(x, (unsigned short*)xb, 784, 832, g);
    g = 1024L * 832 / 4;
    cvt_pad4<<<dim3((g + 255) / 256), dim3(256), 0, stream>>>(W_ih, (unsigned short*)wihb, 784, 832, g);
    pack_heads<<<dim3(1024), dim3(256), 0, stream>>>(W_m, W_lv, W_ap, whead);
    pack_bias3<<<dim3(1), dim3(256), 0, stream>>>(b_m, b_lv, b_ap, bhead);
    g = 1024L * 64 / 4;
    cvt_pad4<<<dim3((g + 255) / 256), dim3(256), 0, stream>>>(W_lh, (unsigned short*)wlhb, 64, 64, g);
    g = 1024L * 1024 / 4;
    cvt_rows4<<<dim3((g + 255) / 256), dim3(256), 0, stream>>>(W_ho, (unsigned short*)whob, 784, g);
    pad_vec<<<dim3(4), dim3(256), 0, stream>>>(b_ho, bho, 784, 1024);

    // ---- encode: hidden = tanh(x @ W_ih^T + b_ih) -> bf16 [B,1024] (Kp=832, 13 tiles) ----
    mgemm8<1><<<dim3(64, 4), dim3(512), 0, stream>>>(xb, wihb, b_ih, hb, 832, 832, 13, 1024, 1024);

    // ---- heads: [mean|logvar|approx] = hidden @ Whead^T -> fp32 planes ----
    mgemm<0><<<dim3(128, 2), dim3(256), 0, stream>>>(hb, whead, bhead, mean, 1024, 1024, 32, 0, 192);

    // ---- reparameterize ----
    reparam_kernel<<<dim3((B * 64) / 256), dim3(256), 0, stream>>>(mean, logvar, approx, eps, z, zb, B);

    // ---- decode: h2 = tanh(z @ W_lh^T + b_lh) -> bf16 [B,1024] ----
    mgemm<1><<<dim3(128, 8), dim3(256), 0, stream>>>(zb, wlhb, b_lh, h2b, 64, 64, 2, 1024, 1024);

    // ---- output: x_mean = sigmoid(h2 @ W_ho^T + b_ho) -> fp32 [B,784] (16 tiles) ----
    mgemm8<2><<<dim3(64, 4), dim3(512), 0, stream>>>(h2b, whob, bho, x_mean, 1024, 1024, 16, 784, 784);
}

// Round 9
// 160.459 us; speedup vs baseline: 6.3470x; 1.0411x over previous
//
#include <hip/hip_runtime.h>
#include <hip/hip_bf16.h>
#include <math.h>

typedef __attribute__((ext_vector_type(8))) short short8;
typedef __attribute__((ext_vector_type(4))) float f32x4;
typedef __attribute__((ext_vector_type(4))) unsigned short us4;

#define GLOBAL_AS __attribute__((address_space(1)))
#define LDS_AS __attribute__((address_space(3)))

__device__ inline void g2l16(const void* g, void* l) {
    __builtin_amdgcn_global_load_lds((const GLOBAL_AS void*)g, (LDS_AS void*)l, 16, 0, 0);
}

__device__ inline unsigned short f2bf(float f) {   // RNE, matches __float2bfloat16 for finite
    unsigned int u = __float_as_uint(f);
    return (unsigned short)((u + 0x7fffu + ((u >> 16) & 1u)) >> 16);
}

// ---------------------------------------------------------------------------
// 256x128 MFMA GEMM, BK=32, counted vmcnt, 48 KiB LDS -> 3 blocks/CU.
// Rationale (r8 post-mortem): encode(13 tiles) == output(16 tiles) in time ->
// per-tile cost ~0, walls are block-fixed costs exposed at 1 block/CU
// (128KB LDS). Shrink LDS so 2-3 blocks co-reside; block-level TLP hides
// prologue/sync/epilogue (m114/m97 mechanism). Keep proven pieces: coalesced
// XOR-swizzled staging (g(row)=(row>>1)&3, 0 bank conflicts), counted
// vmcnt(3) 2-deep pipeline, setprio around MFMA cluster.
// 8 waves as 4M x 2N, wave tile 64x64, acc 4x4 frags.
// LDS per buf: A[256 rows][4 c2] 16KB + B[128][4] 8KB = 24KB; x2 = 48KB.
// stage: 2 A-gloads + 1 B-gload per thread; slot s -> row=s>>2,
//        src chunk=(s&3)^((row>>1)&3)  (16 cache lines per wave-instr).
// read:  frag (R,h) at slot R*4 + (h^((r0>>1)&3)) -> all 8 bank-quartets
//        hit 2x per 16-lane group; sharing lanes 512B apart = free (m136).
// loop t: vmcnt(3) [tail 0] -> barrier -> 8 ds_read + 16 MFMA -> barrier
//         -> stage(t+2) into just-freed buffer.
// EPI: 1 = tanh -> bf16 (ldc cols)   2 = sigmoid -> fp32, cols < Nreal only
// ---------------------------------------------------------------------------
template <int EPI>
__global__ __launch_bounds__(512, 4) void mgemmB(
    const __hip_bfloat16* __restrict__ A,
    const __hip_bfloat16* __restrict__ W,
    const float* __restrict__ bias,
    void* __restrict__ outp,
    int lda, int ldb, int nT, int ldc, int Nreal)
{
    __shared__ __align__(16) __hip_bfloat16 sh[2][12288];   // 48 KiB

    const int tid  = threadIdx.x;
    const int wave = tid >> 6;
    const int lane = tid & 63;
    const int rBase = blockIdx.x * 256;
    const int cBase = blockIdx.y * 128;

    const __hip_bfloat16* Ab = A + (size_t)rBase * lda;
    const __hip_bfloat16* Wb = W + (size_t)cBase * ldb;

    const int wr = (wave >> 1) * 64;    // wave row base (0/64/128/192)
    const int wc = (wave & 1) * 64;     // wave col base (0/64)
    const int h  = lane >> 4;           // chunk-within-kstep 0..3
    const int r0 = lane & 15;
    const int swz = h ^ ((r0 >> 1) & 3);

    f32x4 acc[4][4];
#pragma unroll
    for (int m = 0; m < 4; ++m)
#pragma unroll
        for (int n = 0; n < 4; ++n) acc[m][n] = (f32x4){0.f, 0.f, 0.f, 0.f};

    // stage one BK=32 tile: A 1024 slots (2 gloads), B 512 slots (1 gload)
    auto stage = [&](int bb, int t) {
        const int k0 = t * 32;
#pragma unroll
        for (int r = 0; r < 2; ++r) {
            int s2  = r * 512 + tid;                 // 0..1023
            int row = s2 >> 2;                       // 0..255
            int cg  = (s2 & 3) ^ ((row >> 1) & 3);
            g2l16(Ab + (size_t)row * lda + k0 + cg * 8, &sh[bb][s2 * 8]);
        }
        {
            int s2  = tid;                           // 0..511
            int row = s2 >> 2;                       // 0..127
            int cg  = (s2 & 3) ^ ((row >> 1) & 3);
            g2l16(Wb + (size_t)row * ldb + k0 + cg * 8, &sh[bb][8192 + s2 * 8]);
        }
    };

    auto compute = [&](int bb) {
        const __hip_bfloat16* base = &sh[bb][0];
        short8 a_[4], b_[4];
#pragma unroll
        for (int m = 0; m < 4; ++m) {
            int R = wr + m * 16 + r0;
            a_[m] = *(const short8*)(base + (R * 4 + swz) * 8);
        }
#pragma unroll
        for (int n = 0; n < 4; ++n) {
            int R = wc + n * 16 + r0;
            b_[n] = *(const short8*)(base + 8192 + (R * 4 + swz) * 8);
        }
        __builtin_amdgcn_s_setprio(1);
#pragma unroll
        for (int m = 0; m < 4; ++m)
#pragma unroll
            for (int n = 0; n < 4; ++n)
                acc[m][n] = __builtin_amdgcn_mfma_f32_16x16x32_bf16(a_[m], b_[n], acc[m][n], 0, 0, 0);
        __builtin_amdgcn_s_setprio(0);
    };

    stage(0, 0);
    stage(1, 1);
    for (int t = 0; t < nT; ++t) {
        const int cur = t & 1;
        if (t + 1 < nT) asm volatile("s_waitcnt vmcnt(3)" ::: "memory");  // tile t landed
        else            asm volatile("s_waitcnt vmcnt(0)" ::: "memory");
        __builtin_amdgcn_s_barrier();            // all waves see tile t in LDS
        compute(cur);
        __builtin_amdgcn_s_barrier();            // all waves done reading buf cur
        if (t + 2 < nT) stage(cur, t + 2);       // overwrite freed buffer
    }

    const int rq = lane >> 4;
    const int c0 = lane & 15;
#pragma unroll
    for (int m = 0; m < 4; ++m) {
#pragma unroll
        for (int n = 0; n < 4; ++n) {
            f32x4 v = acc[m][n];
            const int gc = cBase + wc + n * 16 + c0;
            const float bv = bias[gc];
#pragma unroll
            for (int j = 0; j < 4; ++j) {
                const int gr = rBase + wr + m * 16 + rq * 4 + j;
                float val = v[j] + bv;
                if (EPI == 1) {
                    ((__hip_bfloat16*)outp)[(size_t)gr * ldc + gc] = __float2bfloat16(tanhf(val));
                } else {
                    if (gc < Nreal)
                        ((float*)outp)[(size_t)gr * Nreal + gc] = 1.f / (1.f + expf(-val));
                }
            }
        }
    }
}

// ---------------------------------------------------------------------------
// 128x128 MFMA GEMM (4 waves, 2-phase drain) — heads (EPI 0), decode (EPI 1).
// Swizzled staging: layout [row(128)][c2(4)], chunk XOR (row>>1)&3. (r8-proven)
// ---------------------------------------------------------------------------
template <int EPI>
__global__ __launch_bounds__(256) void mgemm(
    const __hip_bfloat16* __restrict__ A,
    const __hip_bfloat16* __restrict__ W,
    const float* __restrict__ bias,
    void* __restrict__ outp,
    int lda, int ldb, int nT, int ldc, int Nreal)
{
    __shared__ __align__(16) __hip_bfloat16 sh[2][8192];

    const int tid  = threadIdx.x;
    const int wave = tid >> 6;
    const int lane = tid & 63;
    const int rBase = blockIdx.x * 128;
    const int cBase = blockIdx.y * 128;

    const __hip_bfloat16* Ab = A + (size_t)rBase * lda;
    const __hip_bfloat16* Wb = W + (size_t)cBase * ldb;

    const int wr = (wave >> 1) * 64;
    const int wc = (wave & 1) * 64;
    const int h  = lane >> 4;
    const int r0 = lane & 15;
    const int swz = h ^ ((r0 >> 1) & 3);

    f32x4 acc[4][4];
#pragma unroll
    for (int m = 0; m < 4; ++m)
#pragma unroll
        for (int n = 0; n < 4; ++n) acc[m][n] = (f32x4){0.f, 0.f, 0.f, 0.f};

    auto stage = [&](int bb, int k0) {
#pragma unroll
        for (int r = 0; r < 2; ++r) {
            int s2  = r * 256 + tid;           // 0..511
            int row = s2 >> 2;
            int cg  = (s2 & 3) ^ ((row >> 1) & 3);
            g2l16(Ab + (size_t)row * lda + k0 + cg * 8, &sh[bb][s2 * 8]);
            g2l16(Wb + (size_t)row * ldb + k0 + cg * 8, &sh[bb][4096 + s2 * 8]);
        }
    };

    auto compute = [&](int bb) {
        const __hip_bfloat16* base = &sh[bb][0];
        short8 a_[4], b_[4];
#pragma unroll
        for (int m = 0; m < 4; ++m) {
            int R = wr + m * 16 + r0;
            a_[m] = *(const short8*)(base + (R * 4 + swz) * 8);
        }
#pragma unroll
        for (int n = 0; n < 4; ++n) {
            int R = wc + n * 16 + r0;
            b_[n] = *(const short8*)(base + 4096 + (R * 4 + swz) * 8);
        }
#pragma unroll
        for (int m = 0; m < 4; ++m)
#pragma unroll
            for (int n = 0; n < 4; ++n)
                acc[m][n] = __builtin_amdgcn_mfma_f32_16x16x32_bf16(a_[m], b_[n], acc[m][n], 0, 0, 0);
    };

    stage(0, 0);
    __syncthreads();
    int cur = 0;
    for (int t = 0; t < nT; ++t) {
        if (t + 1 < nT) stage(cur ^ 1, (t + 1) * 32);
        compute(cur);
        __syncthreads();
        cur ^= 1;
    }

    const int rq = lane >> 4;
    const int c0 = lane & 15;
#pragma unroll
    for (int m = 0; m < 4; ++m) {
#pragma unroll
        for (int n = 0; n < 4; ++n) {
            f32x4 v = acc[m][n];
            const int gc = cBase + wc + n * 16 + c0;
            const float bv = bias[gc];
#pragma unroll
            for (int j = 0; j < 4; ++j) {
                const int gr = rBase + wr + m * 16 + rq * 4 + j;
                float val = v[j] + bv;
                if (EPI == 0) {
                    const int sel = gc >> 6, cc = gc & 63;
                    if (sel < 3) {
                        if (sel == 1) val = fminf(fmaxf(val, -4.5f), 0.f);
                        ((float*)outp)[(size_t)sel * (16384u * 64u) + (size_t)gr * 64 + cc] = val;
                    }
                } else if (EPI == 1) {
                    ((__hip_bfloat16*)outp)[(size_t)gr * ldc + gc] = __float2bfloat16(tanhf(val));
                }
            }
        }
    }
}

// ---------------------------------------------------------------------------
// Vectorized fp32 -> bf16 conversions.
// ---------------------------------------------------------------------------
__global__ void cvt_pad4(const float* __restrict__ src, unsigned short* __restrict__ dst,
                         int scols, int dcols, long total4)
{
    long i = (long)blockIdx.x * 256 + threadIdx.x;
    if (i >= total4) return;
    long e = i * 4;
    long row = e / dcols;
    int  c = (int)(e - row * dcols);
    us4 o = (us4){0, 0, 0, 0};
    if (c < scols) {
        float4 v = *(const float4*)(src + row * (long)scols + c);
        o.x = f2bf(v.x); o.y = f2bf(v.y); o.z = f2bf(v.z); o.w = f2bf(v.w);
    }
    *(us4*)(dst + e) = o;
}

__global__ void cvt_rows4(const float* __restrict__ src, unsigned short* __restrict__ dst,
                          int srows, long total4)
{
    long i = (long)blockIdx.x * 256 + threadIdx.x;
    if (i >= total4) return;
    long e = i * 4;
    int r = (int)(e >> 10), c = (int)(e & 1023);
    us4 o = (us4){0, 0, 0, 0};
    if (r < srows) {
        float4 v = *(const float4*)(src + (size_t)r * 1024 + c);
        o.x = f2bf(v.x); o.y = f2bf(v.y); o.z = f2bf(v.z); o.w = f2bf(v.w);
    }
    *(us4*)(dst + e) = o;
}

__global__ void pack_heads(const float* __restrict__ Wm, const float* __restrict__ Wlv,
                           const float* __restrict__ Wap, __hip_bfloat16* __restrict__ dst)
{
    int i = blockIdx.x * 256 + threadIdx.x;
    int r = i >> 10, c = i & 1023;
    float v = 0.f;
    if (r < 64)       v = Wm[(size_t)r * 1024 + c];
    else if (r < 128) v = Wlv[(size_t)(r - 64) * 1024 + c];
    else if (r < 192) v = Wap[(size_t)(r - 128) * 1024 + c];
    dst[i] = __float2bfloat16(v);
}

__global__ void pack_bias3(const float* bm, const float* blv, const float* bap, float* dst)
{
    int i = threadIdx.x;
    float v = 0.f;
    if (i < 64)       v = bm[i];
    else if (i < 128) v = blv[i - 64];
    else if (i < 192) v = bap[i - 128];
    dst[i] = v;
}

__global__ void pad_vec(const float* src, float* dst, int n, int total)
{
    int i = blockIdx.x * 256 + threadIdx.x;
    if (i >= total) return;
    dst[i] = (i < n) ? src[i] : 0.f;
}

// ---------------------------------------------------------------------------
// Reparameterization (closed-form rank-1; verified) + bf16 z copy
// ---------------------------------------------------------------------------
__global__ __launch_bounds__(256) void reparam_kernel(
    const float* __restrict__ mean, const float* __restrict__ logvar,
    const float* __restrict__ approx, const float* __restrict__ eps,
    float* __restrict__ z, __hip_bfloat16* __restrict__ zb, int B)
{
    const int gid  = blockIdx.x * 256 + threadIdx.x;
    const int row  = gid >> 6;
    const int lane = threadIdx.x & 63;
    if (row >= B) return;

    const size_t idx = (size_t)row * 64 + lane;
    const float m  = mean[idx];
    const float lv = logvar[idx];
    const float a  = approx[idx];
    const float ep = eps[idx];

    const float s  = expf(-lv);
    const float x1 = a * a * s;
    const float x2 = s * a * ep;

    float R = x1, S = x2;
#pragma unroll
    for (int off = 1; off < 64; off <<= 1) {
        float r2 = __shfl_down(R, off, 64);
        float s2 = __shfl_down(S, off, 64);
        if (lane + off < 64) { R += r2; S += s2; }
    }
    const float Rexc  = R - x1;
    const float Sexc  = S - x2;
    const float inv1R = 1.f / (1.f + R);
    const float dL    = sqrtf(s * (1.f + Rexc) * inv1R);
    const float bj    = -s * a * inv1R / dL;

    const float zv = m + dL * ep + bj * Sexc;
    z[idx]  = zv;
    zb[idx] = __float2bfloat16(zv);
}

// ---------------------------------------------------------------------------
extern "C" void kernel_launch(void* const* d_in, const int* in_sizes, int n_in,
                              void* d_out, int out_size, void* d_ws, size_t ws_size,
                              hipStream_t stream)
{
    const float* x    = (const float*)d_in[0];
    const float* eps  = (const float*)d_in[1];
    const float* W_ih = (const float*)d_in[2];
    const float* b_ih = (const float*)d_in[3];
    const float* W_m  = (const float*)d_in[4];
    const float* b_m  = (const float*)d_in[5];
    const float* W_lv = (const float*)d_in[6];
    const float* b_lv = (const float*)d_in[7];
    const float* W_ap = (const float*)d_in[8];
    const float* b_ap = (const float*)d_in[9];
    const float* W_lh = (const float*)d_in[10];
    const float* b_lh = (const float*)d_in[11];
    const float* W_ho = (const float*)d_in[12];
    const float* b_ho = (const float*)d_in[13];

    const int B = 16384;

    float* out    = (float*)d_out;
    float* x_mean = out;
    float* z      = out + (size_t)B * 784;
    float* mean   = z + (size_t)B * 64;
    float* logvar = mean + (size_t)B * 64;
    float* approx = logvar + (size_t)B * 64;

    // ---- workspace layout (~65.3 MiB) ----
    char* ws = (char*)d_ws;
    __hip_bfloat16* hb    = (__hip_bfloat16*)(ws + 0);          // [16384,1024] (reused as h2b)
    __hip_bfloat16* xb    = (__hip_bfloat16*)(ws + 33554432);   // [16384,832]
    __hip_bfloat16* wihb  = (__hip_bfloat16*)(ws + 60817408);   // [1024,832]
    __hip_bfloat16* whead = (__hip_bfloat16*)(ws + 62521344);   // [256,1024]
    __hip_bfloat16* wlhb  = (__hip_bfloat16*)(ws + 63045632);   // [1024,64]
    __hip_bfloat16* whob  = (__hip_bfloat16*)(ws + 63176704);   // [896,1024] (slot sized 1024x1024)
    float*          bhead = (float*)(ws + 65273856);            // [256]
    float*          bho   = (float*)(ws + 65274880);            // [896+]
    __hip_bfloat16* h2b   = hb;
    __hip_bfloat16* zb    = xb;   // xb dead after encode

    // ---- conversions / packing ----
    long g;
    g = (long)B * 832 / 4;
    cvt_pad4<<<dim3((g + 255) / 256), dim3(256), 0, stream>>>(x, (unsigned short*)xb, 784, 832, g);
    g = 1024L * 832 / 4;
    cvt_pad4<<<dim3((g + 255) / 256), dim3(256), 0, stream>>>(W_ih, (unsigned short*)wihb, 784, 832, g);
    pack_heads<<<dim3(1024), dim3(256), 0, stream>>>(W_m, W_lv, W_ap, whead);
    pack_bias3<<<dim3(1), dim3(256), 0, stream>>>(b_m, b_lv, b_ap, bhead);
    g = 1024L * 64 / 4;
    cvt_pad4<<<dim3((g + 255) / 256), dim3(256), 0, stream>>>(W_lh, (unsigned short*)wlhb, 64, 64, g);
    g = 896L * 1024 / 4;
    cvt_rows4<<<dim3((g + 255) / 256), dim3(256), 0, stream>>>(W_ho, (unsigned short*)whob, 784, g);
    pad_vec<<<dim3(4), dim3(256), 0, stream>>>(b_ho, bho, 784, 896);

    // ---- encode: hidden = tanh(x @ W_ih^T + b_ih) -> bf16 [B,1024] (Kp=832, 26 BK32 tiles) ----
    mgemmB<1><<<dim3(64, 8), dim3(512), 0, stream>>>(xb, wihb, b_ih, hb, 832, 832, 26, 1024, 1024);

    // ---- heads: [mean|logvar|approx] = hidden @ Whead^T -> fp32 planes ----
    mgemm<0><<<dim3(128, 2), dim3(256), 0, stream>>>(hb, whead, bhead, mean, 1024, 1024, 32, 0, 192);

    // ---- reparameterize ----
    reparam_kernel<<<dim3((B * 64) / 256), dim3(256), 0, stream>>>(mean, logvar, approx, eps, z, zb, B);

    // ---- decode: h2 = tanh(z @ W_lh^T + b_lh) -> bf16 [B,1024] ----
    mgemm<1><<<dim3(128, 8), dim3(256), 0, stream>>>(zb, wlhb, b_lh, h2b, 64, 64, 2, 1024, 1024);

    // ---- output: x_mean = sigmoid(h2 @ W_ho^T + b_ho) -> fp32 [B,784] (Np=896, 32 tiles) ----
    mgemmB<2><<<dim3(64, 7), dim3(512), 0, stream>>>(h2b, whob, bho, x_mean, 1024, 1024, 32, 784, 784);
}

// Round 11
// 158.404 us; speedup vs baseline: 6.4293x; 1.0130x over previous
//
#include <hip/hip_runtime.h>
#include <hip/hip_bf16.h>
#include <math.h>

typedef __attribute__((ext_vector_type(8))) short short8;
typedef __attribute__((ext_vector_type(4))) float f32x4;
typedef __attribute__((ext_vector_type(4))) unsigned short us4;

#define GLOBAL_AS __attribute__((address_space(1)))
#define LDS_AS __attribute__((address_space(3)))

__device__ inline void g2l16(const void* g, void* l) {
    __builtin_amdgcn_global_load_lds((const GLOBAL_AS void*)g, (LDS_AS void*)l, 16, 0, 0);
}

__device__ inline unsigned short f2bf(float f) {   // RNE, matches __float2bfloat16 for finite
    unsigned int u = __float_as_uint(f);
    return (unsigned short)((u + 0x7fffu + ((u >> 16) & 1u)) >> 16);
}

#define FENCE asm volatile("" ::: "memory")
#define BAR __builtin_amdgcn_s_barrier()

// ---------------------------------------------------------------------------
// 256x256 MFMA GEMM — m201 8-phase schedule, BK=64, vmcnt ONLY at ph4/ph8.
// r10 NaN root cause: vmcnt->ds_read->barrier order. vmcnt is PER-WAVE; LDS
// quarters are staged by ALL waves, so reads must come AFTER a barrier that
// joins every wave's vmcnt. Fix: waits at END of ph4/ph8 (before trailing
// barrier), exactly the m201 placement. 1 barrier per phase.
// Hazards (traced):
//  RAW: prologue vmcnt(6)+BAR => tile0 ready for ph1-4. ph4-end vmcnt(6)
//       (oldest 8 of 14 = tile T1) +BAR => ph5-8. ph8-end vmcnt(6) = tile
//       T0+2 +BAR => next ph1. Tail: stages skip at t>=nT; last-iter ph4-end
//       vmcnt(0) drains tile T1's 8 loads; ph8-end wait skipped.
//  WAR: each stage overwrites the quarter last read ONE phase earlier; those
//       ds_reads retired before that phase's MFMA (lgkm) < barrier < stage.
// A-frags (8x short8) load once per k-step, reused across both N-halves.
// Layout (r8-proven): [ks(2)][row(256)][c2(4)] 16B slots, chunk^=(row>>1)&3:
// coalesced staging (16 lines/gload-instr), conflict-free ds_read_b128.
// nT must be EVEN. EPI: 1 = tanh->bf16 (ldc)  2 = sigmoid->fp32 (gc<Nreal)
// ---------------------------------------------------------------------------
template <int EPI>
__global__ __launch_bounds__(512, 2) void mgemmP(
    const __hip_bfloat16* __restrict__ A,
    const __hip_bfloat16* __restrict__ W,
    const float* __restrict__ bias,
    void* __restrict__ outp,
    int lda, int ldb, int nT, int ldc, int Nreal)
{
    __shared__ __align__(16) __hip_bfloat16 sh[2][32768];   // 128 KiB

    const int tid  = threadIdx.x;
    const int wave = tid >> 6;
    const int lane = tid & 63;
    const int rBase = blockIdx.x * 256;
    const int cBase = blockIdx.y * 256;

    const __hip_bfloat16* Ab = A + (size_t)rBase * lda;
    const __hip_bfloat16* Wb = W + (size_t)cBase * ldb;

    const int wr = (wave >> 2) * 128;   // wave row base (0/128)
    const int wc = (wave & 3) * 64;     // wave col base (0/64/128/192)
    const int h  = lane >> 4;
    const int r0 = lane & 15;
    const int swz = h ^ ((r0 >> 1) & 3);

    f32x4 acc[8][4];
#pragma unroll
    for (int m = 0; m < 8; ++m)
#pragma unroll
        for (int n = 0; n < 4; ++n) acc[m][n] = (f32x4){0.f, 0.f, 0.f, 0.f};

    // quarter stagers: 2 gloads each; buffer = t&1; guarded for tail
    auto qA = [&](int t, int ks) {
        if (t >= nT) return;
        const int bb = t & 1, k0 = t * 64 + ks * 32;
#pragma unroll
        for (int r = 0; r < 2; ++r) {
            int s2 = r * 512 + tid, row = s2 >> 2, cg = (s2 & 3) ^ ((row >> 1) & 3);
            g2l16(Ab + (size_t)row * lda + k0 + cg * 8, &sh[bb][(ks * 1024 + s2) * 8]);
        }
    };
    auto qB = [&](int t, int ks) {
        if (t >= nT) return;
        const int bb = t & 1, k0 = t * 64 + ks * 32;
#pragma unroll
        for (int r = 0; r < 2; ++r) {
            int s2 = r * 512 + tid, row = s2 >> 2, cg = (s2 & 3) ^ ((row >> 1) & 3);
            g2l16(Wb + (size_t)row * ldb + k0 + cg * 8, &sh[bb][16384 + (ks * 1024 + s2) * 8]);
        }
    };

    short8 a_[8], b_[2];
    auto dsA = [&](int bb, int ks) {
        const __hip_bfloat16* base = &sh[bb][ks * 8192];
#pragma unroll
        for (int i = 0; i < 8; ++i) {
            int R = wr + i * 16 + r0;
            a_[i] = *(const short8*)(base + (R * 4 + swz) * 8);
        }
    };
    auto dsB = [&](int bb, int ks, int nh) {
        const __hip_bfloat16* base = &sh[bb][16384 + ks * 8192];
#pragma unroll
        for (int j = 0; j < 2; ++j) {
            int R = wc + (nh * 2 + j) * 16 + r0;
            b_[j] = *(const short8*)(base + (R * 4 + swz) * 8);
        }
    };
    auto mma = [&](int nh) {
        __builtin_amdgcn_s_setprio(1);
#pragma unroll
        for (int i = 0; i < 8; ++i)
#pragma unroll
            for (int j = 0; j < 2; ++j)
                acc[i][nh * 2 + j] = __builtin_amdgcn_mfma_f32_16x16x32_bf16(
                    a_[i], b_[j], acc[i][nh * 2 + j], 0, 0, 0);
        __builtin_amdgcn_s_setprio(0);
    };

    // prologue: 7 quarters (tile0 complete; tile1 all but B ks1); wait+join
    qA(0, 0); qB(0, 0); qA(0, 1); qB(0, 1); qA(1, 0); qB(1, 0); qA(1, 1);
    asm volatile("s_waitcnt vmcnt(6)" ::: "memory");   // tile0's 8 loads landed
    FENCE; BAR; FENCE;                                  // joined: tile0 visible

    const int nIter = nT >> 1;
    for (int it = 0; it < nIter; ++it) {
        const int T0 = 2 * it, T1 = 2 * it + 1;
        const bool lastIt = (it == nIter - 1);
        // ph1: buf0 ks0, N-half 0
        dsA(0, 0); dsB(0, 0, 0); qB(T1, 1);
        mma(0);
        FENCE; BAR; FENCE;
        // ph2: buf0 ks0, N-half 1 (A reuse)
        dsB(0, 0, 1); qA(T0 + 2, 0);
        mma(1);
        FENCE; BAR; FENCE;
        // ph3: buf0 ks1, N-half 0
        dsA(0, 1); dsB(0, 1, 0); qB(T0 + 2, 0);
        mma(0);
        FENCE; BAR; FENCE;
        // ph4: buf0 ks1, N-half 1  + wait for tile T1
        dsB(0, 1, 1); qA(T0 + 2, 1);
        mma(1);
        if (lastIt) asm volatile("s_waitcnt vmcnt(0)" ::: "memory");
        else        asm volatile("s_waitcnt vmcnt(6)" ::: "memory");
        FENCE; BAR; FENCE;
        // ph5: buf1 ks0, N-half 0
        dsA(1, 0); dsB(1, 0, 0); qB(T0 + 2, 1);
        mma(0);
        FENCE; BAR; FENCE;
        // ph6: buf1 ks0, N-half 1
        dsB(1, 0, 1); qA(T1 + 2, 0);
        mma(1);
        FENCE; BAR; FENCE;
        // ph7: buf1 ks1, N-half 0
        dsA(1, 1); dsB(1, 1, 0); qB(T1 + 2, 0);
        mma(0);
        FENCE; BAR; FENCE;
        // ph8: buf1 ks1, N-half 1  + wait for tile T0+2 (next iter's buf0)
        dsB(1, 1, 1); qA(T1 + 2, 1);
        mma(1);
        if (!lastIt) asm volatile("s_waitcnt vmcnt(6)" ::: "memory");
        FENCE; BAR; FENCE;
    }

    const int rq = lane >> 4;
    const int c0 = lane & 15;
#pragma unroll
    for (int m = 0; m < 8; ++m) {
#pragma unroll
        for (int n = 0; n < 4; ++n) {
            f32x4 v = acc[m][n];
            const int gc = cBase + wc + n * 16 + c0;
            const float bv = bias[gc];
#pragma unroll
            for (int j = 0; j < 4; ++j) {
                const int gr = rBase + wr + m * 16 + rq * 4 + j;
                float val = v[j] + bv;
                if (EPI == 1) {
                    ((__hip_bfloat16*)outp)[(size_t)gr * ldc + gc] = __float2bfloat16(tanhf(val));
                } else {
                    if (gc < Nreal)
                        ((float*)outp)[(size_t)gr * Nreal + gc] = 1.f / (1.f + expf(-val));
                }
            }
        }
    }
}

// ---------------------------------------------------------------------------
// 128x128 MFMA GEMM (4 waves, 2-phase drain) — heads (EPI 0), decode (EPI 1).
// Swizzled staging: layout [row(128)][c2(4)], chunk XOR (row>>1)&3. (r8/r9)
// ---------------------------------------------------------------------------
template <int EPI>
__global__ __launch_bounds__(256) void mgemm(
    const __hip_bfloat16* __restrict__ A,
    const __hip_bfloat16* __restrict__ W,
    const float* __restrict__ bias,
    void* __restrict__ outp,
    int lda, int ldb, int nT, int ldc, int Nreal)
{
    __shared__ __align__(16) __hip_bfloat16 sh[2][8192];

    const int tid  = threadIdx.x;
    const int wave = tid >> 6;
    const int lane = tid & 63;
    const int rBase = blockIdx.x * 128;
    const int cBase = blockIdx.y * 128;

    const __hip_bfloat16* Ab = A + (size_t)rBase * lda;
    const __hip_bfloat16* Wb = W + (size_t)cBase * ldb;

    const int wr = (wave >> 1) * 64;
    const int wc = (wave & 1) * 64;
    const int h  = lane >> 4;
    const int r0 = lane & 15;
    const int swz = h ^ ((r0 >> 1) & 3);

    f32x4 acc[4][4];
#pragma unroll
    for (int m = 0; m < 4; ++m)
#pragma unroll
        for (int n = 0; n < 4; ++n) acc[m][n] = (f32x4){0.f, 0.f, 0.f, 0.f};

    auto stage = [&](int bb, int k0) {
#pragma unroll
        for (int r = 0; r < 2; ++r) {
            int s2  = r * 256 + tid;
            int row = s2 >> 2;
            int cg  = (s2 & 3) ^ ((row >> 1) & 3);
            g2l16(Ab + (size_t)row * lda + k0 + cg * 8, &sh[bb][s2 * 8]);
            g2l16(Wb + (size_t)row * ldb + k0 + cg * 8, &sh[bb][4096 + s2 * 8]);
        }
    };

    auto compute = [&](int bb) {
        const __hip_bfloat16* base = &sh[bb][0];
        short8 a_[4], b_[4];
#pragma unroll
        for (int m = 0; m < 4; ++m) {
            int R = wr + m * 16 + r0;
            a_[m] = *(const short8*)(base + (R * 4 + swz) * 8);
        }
#pragma unroll
        for (int n = 0; n < 4; ++n) {
            int R = wc + n * 16 + r0;
            b_[n] = *(const short8*)(base + 4096 + (R * 4 + swz) * 8);
        }
#pragma unroll
        for (int m = 0; m < 4; ++m)
#pragma unroll
            for (int n = 0; n < 4; ++n)
                acc[m][n] = __builtin_amdgcn_mfma_f32_16x16x32_bf16(a_[m], b_[n], acc[m][n], 0, 0, 0);
    };

    stage(0, 0);
    __syncthreads();
    int cur = 0;
    for (int t = 0; t < nT; ++t) {
        if (t + 1 < nT) stage(cur ^ 1, (t + 1) * 32);
        compute(cur);
        __syncthreads();
        cur ^= 1;
    }

    const int rq = lane >> 4;
    const int c0 = lane & 15;
#pragma unroll
    for (int m = 0; m < 4; ++m) {
#pragma unroll
        for (int n = 0; n < 4; ++n) {
            f32x4 v = acc[m][n];
            const int gc = cBase + wc + n * 16 + c0;
            const float bv = bias[gc];
#pragma unroll
            for (int j = 0; j < 4; ++j) {
                const int gr = rBase + wr + m * 16 + rq * 4 + j;
                float val = v[j] + bv;
                if (EPI == 0) {
                    const int sel = gc >> 6, cc = gc & 63;
                    if (sel < 3) {
                        if (sel == 1) val = fminf(fmaxf(val, -4.5f), 0.f);
                        ((float*)outp)[(size_t)sel * (16384u * 64u) + (size_t)gr * 64 + cc] = val;
                    }
                } else if (EPI == 1) {
                    ((__hip_bfloat16*)outp)[(size_t)gr * ldc + gc] = __float2bfloat16(tanhf(val));
                }
            }
        }
    }
}

// ---------------------------------------------------------------------------
// prep1: [x | W_ih] [*,784] -> bf16 [17408,896]; whead pack; bhead; bho pad
// ---------------------------------------------------------------------------
__global__ void prep1(const float* __restrict__ x, const float* __restrict__ Wih,
                      const float* __restrict__ Wm, const float* __restrict__ Wlv,
                      const float* __restrict__ Wap, const float* __restrict__ bm,
                      const float* __restrict__ blv, const float* __restrict__ bap,
                      const float* __restrict__ bho_src,
                      unsigned short* __restrict__ xw,
                      unsigned short* __restrict__ whead,
                      float* __restrict__ bhead, float* __restrict__ bho)
{
    const long SEG0 = 17408L * 224, SEG1 = SEG0 + 65536, SEG2 = SEG1 + 64, SEG3 = SEG2 + 256;
    long u = (long)blockIdx.x * 256 + threadIdx.x;
    if (u < SEG0) {
        long r = u / 224;
        int  c = (int)(u - r * 224) * 4;
        us4 o = (us4){0, 0, 0, 0};
        if (c < 784) {
            const float* src = (r < 16384) ? (x + r * 784) : (Wih + (r - 16384) * 784);
            float4 v = *(const float4*)(src + c);
            o.x = f2bf(v.x); o.y = f2bf(v.y); o.z = f2bf(v.z); o.w = f2bf(v.w);
        }
        *(us4*)(xw + r * 896 + c) = o;
    } else if (u < SEG1) {
        long t = u - SEG0;
        int r = (int)(t >> 8), c = (int)(t & 255) * 4;
        us4 o = (us4){0, 0, 0, 0};
        const float* src = nullptr;
        if (r < 64)       src = Wm + (size_t)r * 1024;
        else if (r < 128) src = Wlv + (size_t)(r - 64) * 1024;
        else if (r < 192) src = Wap + (size_t)(r - 128) * 1024;
        if (src) {
            float4 v = *(const float4*)(src + c);
            o.x = f2bf(v.x); o.y = f2bf(v.y); o.z = f2bf(v.z); o.w = f2bf(v.w);
        }
        *(us4*)(whead + (size_t)r * 1024 + c) = o;
    } else if (u < SEG2) {
        int base = (int)(u - SEG1) * 4;
#pragma unroll
        for (int k = 0; k < 4; ++k) {
            int p = base + k;
            float v = 0.f;
            if (p < 64)       v = bm[p];
            else if (p < 128) v = blv[p - 64];
            else if (p < 192) v = bap[p - 128];
            bhead[p] = v;
        }
    } else if (u < SEG3) {
        int base = (int)(u - SEG2) * 4;
#pragma unroll
        for (int k = 0; k < 4; ++k) {
            int p = base + k;
            bho[p] = (p < 784) ? bho_src[p] : 0.f;
        }
    }
}

// prep2 (after encode; writes into dead xb space): whob [1024,1024], wlhb [1024,64]
__global__ void prep2(const float* __restrict__ Who, const float* __restrict__ Wlh,
                      unsigned short* __restrict__ whob, unsigned short* __restrict__ wlhb)
{
    const long SEG0 = 262144, SEG1 = SEG0 + 16384;
    long u = (long)blockIdx.x * 256 + threadIdx.x;
    if (u < SEG0) {
        int r = (int)(u >> 8), c = (int)(u & 255) * 4;
        us4 o = (us4){0, 0, 0, 0};
        if (r < 784) {
            float4 v = *(const float4*)(Who + (size_t)r * 1024 + c);
            o.x = f2bf(v.x); o.y = f2bf(v.y); o.z = f2bf(v.z); o.w = f2bf(v.w);
        }
        *(us4*)(whob + (size_t)r * 1024 + c) = o;
    } else if (u < SEG1) {
        long t = u - SEG0;
        int r = (int)(t >> 4), c = (int)(t & 15) * 4;
        float4 v = *(const float4*)(Wlh + (size_t)r * 64 + c);
        us4 o;
        o.x = f2bf(v.x); o.y = f2bf(v.y); o.z = f2bf(v.z); o.w = f2bf(v.w);
        *(us4*)(wlhb + (size_t)r * 64 + c) = o;
    }
}

// ---------------------------------------------------------------------------
// Reparameterization (closed-form rank-1; verified) + bf16 z copy
// ---------------------------------------------------------------------------
__global__ __launch_bounds__(256) void reparam_kernel(
    const float* __restrict__ mean, const float* __restrict__ logvar,
    const float* __restrict__ approx, const float* __restrict__ eps,
    float* __restrict__ z, __hip_bfloat16* __restrict__ zb, int B)
{
    const int gid  = blockIdx.x * 256 + threadIdx.x;
    const int row  = gid >> 6;
    const int lane = threadIdx.x & 63;
    if (row >= B) return;

    const size_t idx = (size_t)row * 64 + lane;
    const float m  = mean[idx];
    const float lv = logvar[idx];
    const float a  = approx[idx];
    const float ep = eps[idx];

    const float s  = expf(-lv);
    const float x1 = a * a * s;
    const float x2 = s * a * ep;

    float R = x1, S = x2;
#pragma unroll
    for (int off = 1; off < 64; off <<= 1) {
        float r2 = __shfl_down(R, off, 64);
        float s2 = __shfl_down(S, off, 64);
        if (lane + off < 64) { R += r2; S += s2; }
    }
    const float Rexc  = R - x1;
    const float Sexc  = S - x2;
    const float inv1R = 1.f / (1.f + R);
    const float dL    = sqrtf(s * (1.f + Rexc) * inv1R);
    const float bj    = -s * a * inv1R / dL;

    const float zv = m + dL * ep + bj * Sexc;
    z[idx]  = zv;
    zb[idx] = __float2bfloat16(zv);
}

// ---------------------------------------------------------------------------
extern "C" void kernel_launch(void* const* d_in, const int* in_sizes, int n_in,
                              void* d_out, int out_size, void* d_ws, size_t ws_size,
                              hipStream_t stream)
{
    const float* x    = (const float*)d_in[0];
    const float* eps  = (const float*)d_in[1];
    const float* W_ih = (const float*)d_in[2];
    const float* b_ih = (const float*)d_in[3];
    const float* W_m  = (const float*)d_in[4];
    const float* b_m  = (const float*)d_in[5];
    const float* W_lv = (const float*)d_in[6];
    const float* b_lv = (const float*)d_in[7];
    const float* W_ap = (const float*)d_in[8];
    const float* b_ap = (const float*)d_in[9];
    const float* W_lh = (const float*)d_in[10];
    const float* b_lh = (const float*)d_in[11];
    const float* W_ho = (const float*)d_in[12];
    const float* b_ho = (const float*)d_in[13];

    const int B = 16384;

    float* out    = (float*)d_out;
    float* x_mean = out;
    float* z      = out + (size_t)B * 784;
    float* mean   = z + (size_t)B * 64;
    float* logvar = mean + (size_t)B * 64;
    float* approx = logvar + (size_t)B * 64;

    // ---- workspace layout (<= 65.3 MB proven) ----
    char* ws = (char*)d_ws;
    __hip_bfloat16* hb    = (__hip_bfloat16*)(ws + 0);          // [16384,1024] (reused as h2b)
    __hip_bfloat16* xb    = (__hip_bfloat16*)(ws + 33554432);   // [17408,896]: x rows then W_ih rows
    __hip_bfloat16* wihb  = (__hip_bfloat16*)(ws + 62914560);   // = xb + 16384 rows
    __hip_bfloat16* whead = (__hip_bfloat16*)(ws + 64749568);   // [256,1024]
    float*          bhead = (float*)(ws + 65273856);            // [256]
    float*          bho   = (float*)(ws + 65274880);            // [1024]
    // after encode, xb region is dead; reuse it:
    __hip_bfloat16* zb    = (__hip_bfloat16*)(ws + 33554432);   // [16384,64]
    __hip_bfloat16* whob  = (__hip_bfloat16*)(ws + 37748736);   // [1024,1024]
    __hip_bfloat16* wlhb  = (__hip_bfloat16*)(ws + 39845888);   // [1024,64]
    __hip_bfloat16* h2b   = hb;

    // ---- prep1 ----
    {
        long total = 17408L * 224 + 65536 + 64 + 256;
        prep1<<<dim3((total + 255) / 256), dim3(256), 0, stream>>>(
            x, W_ih, W_m, W_lv, W_ap, b_m, b_lv, b_ap, b_ho,
            (unsigned short*)xb, (unsigned short*)whead, bhead, bho);
    }

    // ---- encode: hidden = tanh(x @ W_ih^T + b_ih) -> bf16 [B,1024] (Kp=896, 14 tiles) ----
    mgemmP<1><<<dim3(64, 4), dim3(512), 0, stream>>>(xb, wihb, b_ih, hb, 896, 896, 14, 1024, 1024);

    // ---- prep2 (into dead xb space): whob, wlhb ----
    prep2<<<dim3((262144 + 16384 + 255) / 256), dim3(256), 0, stream>>>(
        W_ho, W_lh, (unsigned short*)whob, (unsigned short*)wlhb);

    // ---- heads: [mean|logvar|approx] = hidden @ Whead^T -> fp32 planes ----
    mgemm<0><<<dim3(128, 2), dim3(256), 0, stream>>>(hb, whead, bhead, mean, 1024, 1024, 32, 0, 192);

    // ---- reparameterize ----
    reparam_kernel<<<dim3((B * 64) / 256), dim3(256), 0, stream>>>(mean, logvar, approx, eps, z, zb, B);

    // ---- decode: h2 = tanh(z @ W_lh^T + b_lh) -> bf16 [B,1024] ----
    mgemm<1><<<dim3(128, 8), dim3(256), 0, stream>>>(zb, wlhb, b_lh, h2b, 64, 64, 2, 1024, 1024);

    // ---- output: x_mean = sigmoid(h2 @ W_ho^T + b_ho) -> fp32 [B,784] (16 tiles) ----
    mgemmP<2><<<dim3(64, 4), dim3(512), 0, stream>>>(h2b, whob, bho, x_mean, 1024, 1024, 16, 784, 784);
}